// Round 9
// baseline (481.214 us; speedup 1.0000x reference)
//
#include <hip/hip_runtime.h>
#include <hip/hip_bf16.h>
#include <stdint.h>

typedef __bf16 bf16;
typedef __bf16 bf16x8 __attribute__((ext_vector_type(8)));
typedef __bf16 bf16x4 __attribute__((ext_vector_type(4)));
typedef float f32x4 __attribute__((ext_vector_type(4)));

#define AS1 __attribute__((address_space(1)))
#define AS3 __attribute__((address_space(3)))

// B=4, S=256, H=12, DH=64(pad 128), D=768, FD=2048, FU=2048
// R28 (this round): R26/R27 showed LDS-read time + MFMA time ADD on this
// structure (105=51+48, 115=63+51) regardless of occupancy/barriers. Fix =
// reduce LDS demand: gemm_fp4 loads the B fragments DIRECTLY global->reg
// (L2-resident panel in the z-slab layout, line-coalesced 16B/lane), register
// ping-pong (b0/b1, compile-time alternation), prefetch 1 step ahead under
// counted vmcnt(12). A stays in LDS (proven gld16+XOR). LDS reads/wave-step
// 24->16; LDS 128->64 KiB. BM=BN=256, BK=64, grid (8,4,8).

__device__ __forceinline__ void gld16(const bf16* g, bf16* l) {
  __builtin_amdgcn_global_load_lds((AS1 void*)g, (AS3 void*)l, 16, 0, 0);
}

__global__ void k_sentinel(float* __restrict__ out) {
  int i = blockIdx.x * 256 + threadIdx.x;
  if (i < 2097152) out[i] = 1048576.0f;
}

// ---------------- merged elementwise prep ----------------
// sections (256-thr blocks): s0 invln[1], s1 encWb[1536], s2 probsT[3072],
// s3 maskb[4096], s4 WOb[1152], s5 Xb[768], s6 BgTail[1536]  -> 12161 blocks
__global__ void k_prep(const float* __restrict__ lns, float* __restrict__ invln,
                       const float* __restrict__ enc_W, bf16* __restrict__ encWb,
                       const float* __restrict__ probs, bf16* __restrict__ probsT,
                       const int* __restrict__ cmask, bf16* __restrict__ maskb,
                       const float* __restrict__ W_O, bf16* __restrict__ WOb,
                       const float* __restrict__ resid, bf16* __restrict__ Xb,
                       bf16* __restrict__ BgTail, long ldTail) {
  const int bid = blockIdx.x, t = threadIdx.x;
  if (bid < 1) {                                  // s0: invln (1024)
    for (int k = 0; k < 4; k++) { int j = t + k * 256; invln[j] = 1.0f / lns[j]; }
  } else if (bid < 1537) {                        // s1: encWb cast (393216 v4)
    long idx = ((long)(bid - 1) * 256 + t) * 4;
    float4 v = *(const float4*)(enc_W + idx);
    bf16x4 o; o[0]=(bf16)v.x; o[1]=(bf16)v.y; o[2]=(bf16)v.z; o[3]=(bf16)v.w;
    *(bf16x4*)(encWb + idx) = o;
  } else if (bid < 4609) {                        // s2: probsT (786432 v4)
    long idx = ((long)(bid - 1537) * 256 + t) * 4;
    int s = (int)(idx & 255), q = (int)((idx >> 8) & 255);
    int hb = (int)(idx >> 16), h = hb % 12, b = hb / 12;
    float4 v = *(const float4*)(probs + idx);
    bf16x4 o; o[0]=(bf16)v.x; o[1]=(bf16)v.y; o[2]=(bf16)v.z; o[3]=(bf16)v.w;
    *(bf16x4*)(probsT + (long)b * 786432 + (long)q * 3072 + h * 256 + s) = o;
  } else if (bid < 8705) {                        // s3: maskb (1048576 v4)
    long idx = ((long)(bid - 4609) * 256 + t) * 4;
    int4 v = *(const int4*)(cmask + idx);
    bf16x4 o; o[0]=(bf16)(float)v.x; o[1]=(bf16)(float)v.y;
    o[2]=(bf16)(float)v.z; o[3]=(bf16)(float)v.w;
    *(bf16x4*)(maskb + idx) = o;
  } else if (bid < 9857) {                        // s4: WOb (294912 v4)
    long idx = ((long)(bid - 8705) * 256 + t) * 4;
    int o = (int)(idx % 768), r = (int)((idx / 768) & 127), h = (int)(idx / (768 * 128));
    bf16x4 ov;
    if (r < 64) {
      float4 v = *(const float4*)(W_O + (long)(h * 64 + r) * 768 + o);
      ov[0]=(bf16)v.x; ov[1]=(bf16)v.y; ov[2]=(bf16)v.z; ov[3]=(bf16)v.w;
    } else { ov[0]=ov[1]=ov[2]=ov[3]=(bf16)0.0f; }
    *(bf16x4*)(WOb + idx) = ov;
  } else if (bid < 10625) {                       // s5: Xb (196608 v4)
    long idx = ((long)(bid - 9857) * 256 + t) * 4;
    float il = 1.0f / lns[idx / 768];
    float4 v = *(const float4*)(resid + idx);
    bf16x4 o; o[0]=(bf16)(v.x*il); o[1]=(bf16)(v.y*il);
    o[2]=(bf16)(v.z*il); o[3]=(bf16)(v.w*il);
    *(bf16x4*)(Xb + idx) = o;
  } else {                                        // s6: B_g K-tail (393216 v4)
    long idx = ((long)(bid - 10625) * 256 + t) * 4;
    int f = (int)(idx / 768), d = (int)(idx % 768);
    float4 v = *(const float4*)(enc_W + idx);
    bf16x4 o; o[0]=(bf16)v.x; o[1]=(bf16)v.y; o[2]=(bf16)v.z; o[3]=(bf16)v.w;
    *(bf16x4*)(BgTail + (long)f * ldTail + d) = o;
  }
}

// ---------------- merged tiled transposes ----------------
// zones: WVt[1152] WOt[576] updWt[1536] Ut[2048] -> 5312 blocks
__global__ void k_prepT(const float* __restrict__ wv, bf16* __restrict__ WVt,
                        const float* __restrict__ wo, bf16* __restrict__ W_Ot,
                        const float* __restrict__ updW, bf16* __restrict__ updWt,
                        const float* __restrict__ pr, const float* __restrict__ lns,
                        bf16* __restrict__ Ut) {
  __shared__ float tile[32][33];
  const int bid = blockIdx.x;
  int lane = threadIdx.x & 31, rg = threadIdx.x >> 5;
  if (bid < 1152) {                 // WVt[h][k<128][i<768] = W_V[h,i,k]
    int r0 = bid;
    int x = r0 % 4, y = (r0 / 4) % 24, h = r0 / 96;
    int k0 = x * 32, i0 = y * 32;
    if (k0 < 64) {
      for (int r = rg; r < 32; r += 8)
        tile[r][lane] = wv[((long)(h * 768 + i0 + r)) * 64 + k0 + lane];
      __syncthreads();
      for (int r = rg; r < 32; r += 8)
        WVt[((long)h * 128 + k0 + r) * 768 + i0 + lane] = (bf16)tile[lane][r];
    } else {
      for (int r = rg; r < 32; r += 8)
        WVt[((long)h * 128 + k0 + r) * 768 + i0 + lane] = (bf16)0.0f;
    }
  } else if (bid < 1728) {          // W_Ot[h][o][k64] = W_O[h,k,o]
    int r0 = bid - 1152;
    int x = r0 % 2, y = (r0 / 2) % 24, h = r0 / 48;
    int k0 = x * 32, o0 = y * 32;
    for (int r = rg; r < 32; r += 8)
      tile[r][lane] = wo[((long)(h * 64 + k0 + r)) * 768 + o0 + lane];
    __syncthreads();
    for (int r = rg; r < 32; r += 8)
      W_Ot[((long)(h * 768 + o0 + r)) * 64 + k0 + lane] = (bf16)tile[lane][r];
  } else if (bid < 3264) {          // updWt[u][i] = up_dec_W[i][u]
    int r0 = bid - 1728;
    int u0 = (r0 % 64) * 32, i0 = (r0 / 64) * 32;
    for (int r = rg; r < 32; r += 8)
      tile[r][lane] = updW[((long)(i0 + r)) * 2048 + u0 + lane];
    __syncthreads();
    for (int r = rg; r < 32; r += 8)
      updWt[((long)(u0 + r)) * 768 + i0 + lane] = (bf16)tile[lane][r];
  } else {                          // Ut[b][u][s] = pruned[b,s,u]/ln
    int r0 = bid - 3264;
    int u0 = (r0 % 64) * 32, s0 = ((r0 / 64) % 8) * 32, b = r0 / 512;
    for (int r = rg; r < 32; r += 8) {
      int s = s0 + r;
      tile[r][lane] = pr[((long)(b * 256 + s)) * 2048 + u0 + lane] *
                      (1.0f / lns[b * 256 + s]);
    }
    __syncthreads();
    for (int r = rg; r < 32; r += 8)
      Ut[((long)b * 2048 + u0 + r) * 256 + s0 + lane] = (bf16)tile[lane][r];
  }
}

// reduce 4 fp32 split-K slabs of S and cast into the bf16 A_g K-tail
__global__ void k_sred(const float* __restrict__ Sp, bf16* __restrict__ dst, long ldd) {
  int i = blockIdx.x * 256 + threadIdx.x;   // 196608 vec4s
  if (i < 196608) {
    long idx = (long)i * 4;
    int m = (int)(idx / 768), o = (int)(idx % 768);
    float4 v = *(const float4*)(Sp + idx);
    float4 a = *(const float4*)(Sp + 786432 + idx);
    float4 b = *(const float4*)(Sp + 2 * 786432 + idx);
    float4 c = *(const float4*)(Sp + 3 * 786432 + idx);
    v.x += a.x + b.x + c.x; v.y += a.y + b.y + c.y;
    v.z += a.z + b.z + c.z; v.w += a.w + b.w + c.w;
    bf16x4 ov;
    ov[0] = (bf16)v.x; ov[1] = (bf16)v.y; ov[2] = (bf16)v.z; ov[3] = (bf16)v.w;
    *(bf16x4*)(dst + (long)m * ldd + o) = ov;
  }
}

// ---------------- bias chain (fp32, block-parallel) ----------------

__device__ __forceinline__ float blk_reduce(float s) {
  __shared__ float red[256];
  red[threadIdx.x] = s; __syncthreads();
  for (int o = 128; o > 0; o >>= 1) {
    if ((int)threadIdx.x < o) red[threadIdx.x] += red[threadIdx.x + o];
    __syncthreads();
  }
  float r = red[0]; __syncthreads();
  return r;
}

__global__ void k_bias_t(const float* __restrict__ W_V, const float* __restrict__ up_b,
                         float* __restrict__ t_hk) {
  int j = blockIdx.x, h = j >> 6, k = j & 63;
  float s = 0.f;
  for (int m = threadIdx.x; m < 768; m += 256)
    s += W_V[((long)(h * 768 + m)) * 64 + k] * up_b[m];
  float r = blk_reduce(s);
  if (threadIdx.x == 0) t_hk[j] = r;
}

__global__ void k_bias_w(const float* __restrict__ W_O, const float* __restrict__ t_hk,
                         float* __restrict__ w) {
  int d = blockIdx.x;
  float s = 0.f;
  for (int j = threadIdx.x; j < 768; j += 256)
    s += W_O[(long)j * 768 + d] * t_hk[j];
  float r = blk_reduce(s);
  if (threadIdx.x == 0) w[d] = r;
}

__global__ void k_bias_c(const float* __restrict__ enc_W, const float* __restrict__ enc_b,
                         const float* __restrict__ b_dec, const float* __restrict__ w,
                         float* __restrict__ c0, float* __restrict__ c1) {
  int f = blockIdx.x;
  float s0 = 0.f, s1 = 0.f;
  for (int d = threadIdx.x; d < 768; d += 256) {
    float e = enc_W[(long)f * 768 + d];
    s0 += e * b_dec[d];
    s1 += e * w[d];
  }
  float r0 = blk_reduce(s0);
  float r1 = blk_reduce(s1);
  if (threadIdx.x == 0) { c0[f] = enc_b[f] - r0; c1[f] = r1; }
}

// ---------------- GEMM (BT form: C[m,n] = sum_k A[m,k]*B[n,k]) ----------------
// BK=64, XOR-swizzled staging. K (and kChunk) must be multiples of 64.
// mode 0: bf16 store; mode 1: *= bf16 mask, bf16 store;
// mode 2: split-K fp32 overwrite; mode 3: split-K fp32 read-accumulate;
// mode 4: batched split-K fp32 overwrite (z = bb*batchH + kc, batchH = #kc)
__global__ __launch_bounds__(256)
void gemm_bt(const bf16* __restrict__ A, const bf16* __restrict__ B, void* __restrict__ Cv,
             int M, int N, int K,
             long lda, long ldb, long ldc,
             int batchH,
             long sa_b, long sa_h, long sb_b, long sb_h, long sc_b, long sc_h,
             int mode, int kChunk,
             const bf16* __restrict__ mask, long mask_ld)
{
  __shared__ __align__(16) bf16 Asm[128 * 64];
  __shared__ __align__(16) bf16 Bsm[128 * 64];

  const int t = threadIdx.x;

  // bijective XCD-aware remap of the (x,y) tile id (m204 formula)
  const int nbx = gridDim.x, nby = gridDim.y;
  const int nxy = nbx * nby;
  int orig = blockIdx.x + nbx * blockIdx.y;
  int qq = nxy >> 3, rr = nxy & 7;
  int xcd = orig & 7, lid = orig >> 3;
  int swz = (xcd < rr) ? (xcd * (qq + 1) + lid)
                       : (rr * (qq + 1) + (xcd - rr) * qq + lid);
  const int m0 = (swz % nby) * 128;
  const int n0 = (swz / nby) * 128;

  long aoff, boff, coff;
  int k0, k1;
  if (mode == 4) {
    int z = blockIdx.z;
    int bb = z / batchH, kc = z - bb * batchH;
    aoff = (long)bb * sa_b;
    boff = (long)bb * sb_b;
    coff = (long)bb * sc_b + (long)kc * sc_h;
    k0 = kc * kChunk; k1 = k0 + kChunk; if (k1 > K) k1 = K;
  } else if (mode >= 2) {
    int z = blockIdx.z;
    aoff = 0; boff = 0;
    coff = (long)z * (long)M * ldc;
    k0 = z * kChunk; k1 = k0 + kChunk; if (k1 > K) k1 = K;
  } else {
    int z = blockIdx.z;
    int bb = z / batchH, hh = z - bb * batchH;
    aoff = (long)bb * sa_b + (long)hh * sa_h;
    boff = (long)bb * sb_b + (long)hh * sb_h;
    coff = (long)bb * sc_b + (long)hh * sc_h;
    k0 = 0; k1 = K;
  }

  const bf16* Ab = A + aoff + (long)m0 * lda;
  const bf16* Bb = B + boff + (long)n0 * ldb;

  const int r0 = t >> 3;           // 0..31 (staging row within 32-row group)
  const int g8 = t & 7;            // staging col-group (LDS slot)

  const int L = t & 63, w = t >> 6;
  const int wm = (w & 1) * 64, wn = (w >> 1) * 64;
  const int r16 = L & 15, q = L >> 4;

  f32x4 acc[4][4];
#pragma unroll
  for (int i = 0; i < 4; i++)
#pragma unroll
    for (int j = 0; j < 4; j++) acc[i][j] = (f32x4){0.f, 0.f, 0.f, 0.f};

  for (int kt = k0; kt < k1; kt += 64) {
#pragma unroll
    for (int j = 0; j < 4; j++) {
      int row = j * 32 + r0;
      int sc = ((g8 ^ (row & 7)) << 3);      // source col swizzle
      gld16(Ab + (long)row * lda + (kt + sc), &Asm[j * 2048 + t * 8]);
      gld16(Bb + (long)row * ldb + (kt + sc), &Bsm[j * 2048 + t * 8]);
    }
    __syncthreads();

#pragma unroll
    for (int h2 = 0; h2 < 2; h2++) {
      bf16x8 af[4], bfr[4];
#pragma unroll
      for (int i = 0; i < 4; i++) {
        int ra = wm + i * 16 + r16;
        af[i]  = *(const bf16x8*)&Asm[ra * 64 + ((((h2 << 2) + q) ^ (ra & 7)) << 3)];
        int rb = wn + i * 16 + r16;
        bfr[i] = *(const bf16x8*)&Bsm[rb * 64 + ((((h2 << 2) + q) ^ (rb & 7)) << 3)];
      }
#pragma unroll
      for (int mi = 0; mi < 4; mi++)
#pragma unroll
        for (int ni = 0; ni < 4; ni++)
          acc[mi][ni] = __builtin_amdgcn_mfma_f32_16x16x32_bf16(af[mi], bfr[ni], acc[mi][ni], 0, 0, 0);
    }
    __syncthreads();
  }

  if (mode >= 2) {
    float* C = (float*)Cv;
#pragma unroll
    for (int mi = 0; mi < 4; mi++)
#pragma unroll
      for (int ni = 0; ni < 4; ni++)
#pragma unroll
        for (int r = 0; r < 4; r++) {
          int gm = m0 + wm + mi * 16 + q * 4 + r;
          int gn = n0 + wn + ni * 16 + r16;
          long idx = coff + (long)gm * ldc + gn;
          float v = acc[mi][ni][r];
          if (mode == 3) v += C[idx];
          C[idx] = v;
        }
  } else {
    bf16* C = (bf16*)Cv;
#pragma unroll
    for (int mi = 0; mi < 4; mi++)
#pragma unroll
      for (int ni = 0; ni < 4; ni++)
#pragma unroll
        for (int r = 0; r < 4; r++) {
          int gm = m0 + wm + mi * 16 + q * 4 + r;
          int gn = n0 + wn + ni * 16 + r16;
          float v = acc[mi][ni][r];
          if (mode == 1) v *= (float)mask[(long)gm * mask_ld + gn];
          C[coff + (long)gm * ldc + gn] = (bf16)v;
        }
  }
}

// ------- 256x256-tile split-K GEMM, B direct from L2 (final GEMM) -----------
// C[m,n] (+)= sum_k A[m,k]*B[n,k], fp32 C. 512 threads = 8 waves (2M x 4N),
// per-wave 128x64 output, acc[8][4]. BK=64.
// A: LDS double-buffer (64 KiB), gld16 + XOR swizzle (proven path).
// B: fragments loaded DIRECTLY global->registers (z-slab keeps the panel
// L2-hot; lanes (r16,q) cover whole 64B lines -> line-coalesced). Register
// ping-pong b0/b1 with compile-time alternation (no runtime-indexed regs),
// prefetched 1 K-step ahead under counted vmcnt(12) (= 4 A-stage + 8 B loads
// issued per step; older ones guaranteed landed). LDS reads/wave-step 24->16.
// Work remap: z = fid % nz -> one K-slab per XCD (R24: FETCH 253->76MB).
// K, kChunk multiples of 64. mode 2 = overwrite, 3 = read-accumulate.
__global__ __launch_bounds__(512, 2)
void gemm_fp4(const bf16* __restrict__ A, const bf16* __restrict__ B,
              float* __restrict__ C,
              int M, int N, int K, long lda, long ldb, long ldc,
              int mode, int kChunk)
{
  __shared__ __align__(16) bf16 SM[2][16384];   // A only: [buf][256*64]

  const int t = threadIdx.x;

  const int nz = gridDim.z;
  int fid = blockIdx.x + gridDim.x * (blockIdx.y + gridDim.y * blockIdx.z);
  const int z  = fid % nz;                 // K-slab, constant per XCD when nz=8
  const int t2 = fid / nz;                 // 0..31 (m,n)-tile within the slab
  const int m0 = (t2 >> 3) * 256;          // 4 m-tiles
  const int n0 = (t2 & 7) * 256;           // 8 n-tiles

  const long coff = (long)z * (long)M * ldc;
  int k0 = z * kChunk, k1 = k0 + kChunk; if (k1 > K) k1 = K;
  const int NT = (k1 > k0) ? (k1 - k0) >> 6 : 0;

  const bf16* Ab = A + (long)m0 * lda + k0;

  const int sr = t >> 3;           // 0..63 staging row within 64-row group
  const int g8 = t & 7;            // staging col-group (LDS slot)

  const int L = t & 63, w = t >> 6;          // 8 waves
  const int wm = (w & 1) * 128;              // 2 waves over M (256)
  const int wn = (w >> 1) * 64;              // 4 waves over N (256)
  const int r16 = L & 15, q = L >> 4;

  // per-lane base pointers for the 4 B fragment rows (16B per lane per load)
  const bf16* Bp0 = B + (long)(n0 + wn + 0 * 16 + r16) * ldb + k0 + q * 8;
  const bf16* Bp1 = B + (long)(n0 + wn + 1 * 16 + r16) * ldb + k0 + q * 8;
  const bf16* Bp2 = B + (long)(n0 + wn + 2 * 16 + r16) * ldb + k0 + q * 8;
  const bf16* Bp3 = B + (long)(n0 + wn + 3 * 16 + r16) * ldb + k0 + q * 8;

  f32x4 acc[8][4];
#pragma unroll
  for (int i = 0; i < 8; i++)
#pragma unroll
    for (int j = 0; j < 4; j++) acc[i][j] = (f32x4){0.f, 0.f, 0.f, 0.f};

  // stage A K-tile tt into buffer buf: 4 gld16 per thread
  auto stageA = [&](int tt, int buf) {
    const bf16* Ap = Ab + (long)tt * 64;
#pragma unroll
    for (int j = 0; j < 4; j++) {
      int row = j * 64 + sr;
      int sc = ((g8 ^ (row & 7)) << 3);
      gld16(Ap + (long)row * lda + sc, &SM[buf][j * 4096 + t * 8]);
    }
  };

  bf16x8 b0[2][4], b1[2][4];

#define LOADB(DST, tt) do {                                         \
    long kk_ = (long)(tt) * 64;                                     \
    DST[0][0] = *(const bf16x8*)(Bp0 + kk_);                        \
    DST[0][1] = *(const bf16x8*)(Bp1 + kk_);                        \
    DST[0][2] = *(const bf16x8*)(Bp2 + kk_);                        \
    DST[0][3] = *(const bf16x8*)(Bp3 + kk_);                        \
    DST[1][0] = *(const bf16x8*)(Bp0 + kk_ + 32);                   \
    DST[1][1] = *(const bf16x8*)(Bp1 + kk_ + 32);                   \
    DST[1][2] = *(const bf16x8*)(Bp2 + kk_ + 32);                   \
    DST[1][3] = *(const bf16x8*)(Bp3 + kk_ + 32);                   \
  } while (0)

#define COMPUTE(BC, ASRC) do {                                      \
    _Pragma("unroll")                                               \
    for (int h2 = 0; h2 < 2; h2++) {                                \
      bf16x8 af[8];                                                 \
      _Pragma("unroll")                                             \
      for (int i = 0; i < 8; i++) {                                 \
        int ra = wm + i * 16 + r16;                                 \
        af[i] = *(const bf16x8*)&(ASRC)[ra * 64 +                   \
                 ((((h2 << 2) + q) ^ (ra & 7)) << 3)];              \
      }                                                             \
      _Pragma("unroll")                                             \
      for (int mi = 0; mi < 8; mi++)                                \
        _Pragma("unroll")                                           \
        for (int ni = 0; ni < 4; ni++)                              \
          acc[mi][ni] = __builtin_amdgcn_mfma_f32_16x16x32_bf16(    \
              af[mi], (BC)[h2][ni], acc[mi][ni], 0, 0, 0);          \
    }                                                               \
  } while (0)

  if (NT >= 1) { stageA(0, 0); LOADB(b0, 0); }

  int tt = 0;
  while (tt < NT) {
    {   // even step: consume b0, prefetch into b1
      bool more = (tt + 1 < NT);
      if (more) {
        stageA(tt + 1, (tt + 1) & 1);
        LOADB(b1, tt + 1);
        asm volatile("s_waitcnt vmcnt(12)" ::: "memory");
      } else {
        asm volatile("s_waitcnt vmcnt(0)" ::: "memory");
      }
      __builtin_amdgcn_s_barrier();
      const bf16* As = &SM[tt & 1][0];
      COMPUTE(b0, As);
      __builtin_amdgcn_s_barrier();
      tt++;
      if (!more) break;
    }
    {   // odd step: consume b1, prefetch into b0
      bool more = (tt + 1 < NT);
      if (more) {
        stageA(tt + 1, (tt + 1) & 1);
        LOADB(b0, tt + 1);
        asm volatile("s_waitcnt vmcnt(12)" ::: "memory");
      } else {
        asm volatile("s_waitcnt vmcnt(0)" ::: "memory");
      }
      __builtin_amdgcn_s_barrier();
      const bf16* As = &SM[tt & 1][0];
      COMPUTE(b1, As);
      __builtin_amdgcn_s_barrier();
      tt++;
      if (!more) break;
    }
  }
#undef LOADB
#undef COMPUTE

#pragma unroll
  for (int mi = 0; mi < 8; mi++)
#pragma unroll
    for (int ni = 0; ni < 4; ni++)
#pragma unroll
      for (int r = 0; r < 4; r++) {
        int gm = m0 + wm + mi * 16 + q * 4 + r;
        int gn = n0 + wn + ni * 16 + r16;
        long idx = coff + (long)gm * ldc + gn;
        float v = acc[mi][ni][r];
        if (mode == 3) v += C[idx];
        C[idx] = v;
      }
}

// ---------------- final reduce + bias epilogue (fp32 out, float4) ------------
__global__ void k_out(const float* __restrict__ Cp, const float* __restrict__ c0,
                      const float* __restrict__ c1, const float* __restrict__ invln,
                      float* __restrict__ out, int nsplit) {
  int i4 = blockIdx.x * 256 + threadIdx.x;          // 524288
  long i = (long)i4 * 4;
  int n = (int)(i & 2047), m = (int)(i >> 11);
  float4 v = *(const float4*)(Cp + i);
  for (int z = 1; z < nsplit; z++) {
    float4 u = *(const float4*)(Cp + i + (long)z * 2097152);
    v.x += u.x; v.y += u.y; v.z += u.z; v.w += u.w;
  }
  float il = invln[m];
  float4 a = *(const float4*)(c0 + n);
  float4 b = *(const float4*)(c1 + n);
  v.x += a.x + b.x * il;
  v.y += a.y + b.y * il;
  v.z += a.z + b.z * il;
  v.w += a.w + b.w * il;
  *(float4*)(out + i) = v;
}

// ---------------- host ----------------

extern "C" void kernel_launch(void* const* d_in, const int* in_sizes, int n_in,
                              void* d_out, int out_size, void* d_ws, size_t ws_size,
                              hipStream_t stream) {
  (void)out_size;
  float* out = (float*)d_out;

  // ---- resolve inputs by size (order-agnostic) ----
  int iresid = -1, iln = -1, iprobs = -1, iencb = -1, ipruned = -1, imask = -1;
  int iwo = -1, iwv = -1, iencw = -1, iupdw = -1, ibdec = -1, iupb = -1;
  for (int i = 0; i < n_in; i++) {
    switch (in_sizes[i]) {
      case 786432:  iresid  = i; break;
      case 1024:    iln     = i; break;
      case 3145728: iprobs  = i; break;
      case 2048:    iencb   = i; break;
      case 2097152: ipruned = i; break;
      case 4194304: imask   = i; break;
      case 589824:  if (iwo   < 0) iwo   = i; else iwv   = i; break;
      case 1572864: if (iencw < 0) iencw = i; else iupdw = i; break;
      case 768:     if (ibdec < 0) ibdec = i; else iupb  = i; break;
      default: break;
    }
  }
  bool ok = n_in == 12 && iresid >= 0 && iln >= 0 && iprobs >= 0 && iencb >= 0 &&
            ipruned >= 0 && imask >= 0 && iwo >= 0 && iwv >= 0 && iencw >= 0 &&
            iupdw >= 0 && ibdec >= 0 && iupb >= 0;
  if (!ok) { k_sentinel<<<8192, 256, 0, stream>>>(out); return; }

  const float* resid = (const float*)d_in[iresid];
  const float* lns   = (const float*)d_in[iln];
  const float* probs = (const float*)d_in[iprobs];
  const float* W_O   = (const float*)d_in[iwo];
  const float* W_V   = (const float*)d_in[iwv];
  const float* enc_W = (const float*)d_in[iencw];
  const float* enc_b = (const float*)d_in[iencb];
  const float* b_dec = (const float*)d_in[ibdec];
  const float* updW  = (const float*)d_in[iupdw];
  const float* up_b  = (const float*)d_in[iupb];
  const float* pruned= (const float*)d_in[ipruned];
  const int*   cmask = (const int*)d_in[imask];

  // ---- workspace sizing ----
  auto pad = [](size_t b) -> size_t { return (b + 255) & ~(size_t)255; };
  const size_t prepB = pad(2359296) + pad(2359296) + pad(3145728) + pad(1572864) +
                       pad(3145728) + pad(1179648) + pad(3145728) + pad(18874368) +
                       pad(12582912);
  const size_t persB = pad(6291456) + pad(4194304) + pad(6291456) + pad(6291456) +
                       pad(8388608) + pad(4096) + pad(3072) + pad(3072) +
                       pad(8192) + pad(8192);
  auto needB = [&](int g, int ns) -> size_t {
    size_t cp = (size_t)ns * 8388608;
    size_t ov = prepB > cp ? prepB : cp;
    long KA = (long)g * 2048 + 768;
    size_t ab = pad((size_t)1024 * KA * 2) + pad((size_t)2048 * KA * 2);
    return ov + persB + ab + (2ull << 20);   // 2MiB slack
  };
  // prefer gs=12 (one final GEMM) + nsplit=8 (grid (8,4,8)=256 blocks = 1/CU)
  const int cgs[14] = {12, 12, 12, 6, 6, 4, 3, 2, 2, 1, 1, 1, 1, 1};
  const int cns[14] = { 8,  4, 2, 8, 4, 4, 4, 4, 2, 8, 4, 2, 2, 1};
  int gs = 0, nsplit = 0;
  for (int ci = 0; ci < 14; ci++) {
    if (needB(cgs[ci], cns[ci]) <= ws_size) { gs = cgs[ci]; nsplit = cns[ci]; break; }
  }
  if (gs == 0) { gs = 1; nsplit = 1; }

  const long KA = (long)gs * 2048 + 768;     // A_g/B_g leading dim (K incl. tail)

  char* p = (char*)d_ws;
  auto alloc = [&](size_t bytes) -> char* {
    char* r = p; p += (bytes + 255) & ~(size_t)255; return r;
  };
  // -- overlay region: prep buffers, later reused as Cpart --
  char* overlayBase = p;
  bf16*  WOb    = (bf16*)alloc(12ull * 128 * 768 * 2);
  bf16*  WVt    = (bf16*)alloc(12ull * 128 * 768 * 2);
  bf16*  updWt  = (bf16*)alloc(2048ull * 768 * 2);
  bf16*  Xb     = (bf16*)alloc(1024ull * 768 * 2);
  bf16*  encWb  = (bf16*)alloc(2048ull * 768 * 2);
  bf16*  W_Ot   = (bf16*)alloc(12ull * 768 * 64 * 2);
  bf16*  T1     = (bf16*)alloc(12ull * 1024 * 128 * 2);
  bf16*  T3     = (bf16*)alloc(4ull * 768 * 3072 * 2);
  float* Sp     = (float*)alloc(4ull * 1024 * 768 * 4);
  {
    size_t used = (size_t)(p - overlayBase);
    size_t cp = (size_t)nsplit * 8388608;
    p = overlayBase + (used > cp ? used : cp);
  }
  float* Cpart  = (float*)overlayBase;       // aliases dead prep buffers
  // -- persistent region --
  bf16*  G_t    = (bf16*)alloc(12ull * 2048 * 128 * 2);
  bf16*  Ut     = (bf16*)alloc(4ull * 2048 * 256 * 2);
  bf16*  E1     = (bf16*)alloc(12ull * 2048 * 128 * 2);
  bf16*  probsT = (bf16*)alloc(4ull * 256 * 3072 * 2);
  bf16*  maskb  = (bf16*)alloc(2048ull * 2048 * 2);
  float* invln  = (float*)alloc(1024 * 4);
  float* t_hk   = (float*)alloc(768 * 4);
  float* wv     = (float*)alloc(768 * 4);
  float* c0     = (float*)alloc(2048 * 4);
  float* c1     = (float*)alloc(2048 * 4);
  bf16*  A_g    = (bf16*)alloc((size_t)1024 * KA * 2);
  bf16*  B_g    = (bf16*)alloc((size_t)2048 * KA * 2);

  // ---- prep (2 merged kernels + bias chain) ----
  k_prep<<<12161, 256, 0, stream>>>(lns, invln, enc_W, encWb, probs, probsT,
                                    cmask, maskb, W_O, WOb, resid, Xb,
                                    B_g + (long)gs * 2048, KA);
  k_prepT<<<5312, 256, 0, stream>>>(W_V, WVt, W_O, W_Ot, updW, updWt,
                                    pruned, lns, Ut);
  k_bias_t<<<768, 256, 0, stream>>>(W_V, up_b, t_hk);
  k_bias_w<<<768, 256, 0, stream>>>(W_O, t_hk, wv);
  k_bias_c<<<2048, 256, 0, stream>>>(enc_W, enc_b, b_dec, wv, c0, c1);

  // Merged E1 + G_t (z = 24, bb selects the problem via pointer-diff strides):
  //   bb=0: E1[h][f][k]  = encWb[f,o] . WOb[h][k][o]
  //   bb=1: G_t[h][u][k] = updWt[u,i] . WVt[h][k][i]
  gemm_bt<<<dim3(1, 16, 24), 256, 0, stream>>>(
      encWb, WOb, E1, 2048, 128, 768,
      768, 768, 128, 12,
      (long)(updWt - encWb), 0,
      (long)(WVt - WOb), (long)128 * 768,
      (long)(G_t - E1), (long)2048 * 128,
      0, 0, nullptr, 0);

  // ---- init path: T1 -> T3 -> S (split-K) -> reduce into A_g K-tail ----
  // T1[h][bs][k128] = Xb[bs,i] . WVt[h][k][i]   M=1024 N=128 K=768 (z=h)
  gemm_bt<<<dim3(1, 8, 12), 256, 0, stream>>>(
      Xb, WVt, T1, 1024, 128, 768,
      768, 768, 128, 12,
      0, 0, 0, (long)128 * 768, 0, (long)1024 * 128,
      0, 0, nullptr, 0);

  // T3[b][o][h*256+s] = W_Ot[h][o][k] . T1[h][b*256+s][k]   M=768 N=256 K=64
  gemm_bt<<<dim3(2, 6, 48), 256, 0, stream>>>(
      W_Ot, T1, T3, 768, 256, 64,
      64, 128, 3072, 12,
      0, (long)768 * 64, (long)256 * 128, (long)1024 * 128, 2359296, 256,
      0, 0, nullptr, 0);

  // S (mode 4, batched split-K): 16 z-blocks, kChunk=768 -> 12 K-steps each.
  gemm_bt<<<dim3(6, 2, 16), 256, 0, stream>>>(
      probsT, T3, Sp, 256, 768, 3072,
      3072, 3072, 768, 4,
      786432, 0, 2359296, 0, 196608, 786432,
      4, 768, nullptr, 0);

  // reduce 4 Sp slabs + cast -> A_g[:, gs*2048 .. +768]
  k_sred<<<768, 256, 0, stream>>>(Sp, A_g + (long)gs * 2048, KA);

  // ---- head-group loop (single iteration when gs==12) ----
  for (int g = 0; g < 12 / gs; g++) {
    // V_g: B_g[f][hh*2048+u] = maskb[f,u] * (E1_h[f,k] . G_t_h[u,k])  K=64
    gemm_bt<<<dim3(16, 16, gs), 256, 0, stream>>>(
        E1 + (long)g * gs * 2048 * 128, G_t + (long)g * gs * 2048 * 128, B_g,
        2048, 2048, 64,
        128, 128, KA, gs,
        0, (long)2048 * 128, 0, (long)2048 * 128, 0, 2048,
        1, 0, maskb, 2048);

    // PU_g: A_g[b*256+q][hh*2048+u] = probsT[b][q][(g*gs+hh)*256 + s] . Ut[b][u][s]
    gemm_bt<<<dim3(16, 2, 4 * gs), 256, 0, stream>>>(
        probsT + (long)g * gs * 256, Ut, A_g,
        256, 2048, 256,
        3072, 256, KA, gs,
        786432, 256, (long)2048 * 256, 0, 256 * KA, 2048,
        0, 0, nullptr, 0);

    // Cpart (+)= A_g[bq,k] . B_g[f,k]  -- 256x256-tile, B-direct-from-L2
    int Kthis = (g == 0) ? (int)KA : gs * 2048;
    int kc = ((Kthis / nsplit + 63) / 64) * 64;
    gemm_fp4<<<dim3(8, 4, nsplit), 512, 0, stream>>>(
        A_g, B_g, Cpart,
        1024, 2048, Kthis,
        KA, KA, 2048,
        (g == 0) ? 2 : 3, kc);
  }

  // out[b,q,f] = fp32( sum_z Cpart + c0[f] + c1[f]*invln[bq] )
  k_out<<<2048, 256, 0, stream>>>(Cpart, c0, c1, invln, out, nsplit);
}

// Round 10
// 436.482 us; speedup vs baseline: 1.1025x; 1.1025x over previous
//
#include <hip/hip_runtime.h>
#include <hip/hip_bf16.h>
#include <stdint.h>

typedef __bf16 bf16;
typedef __bf16 bf16x8 __attribute__((ext_vector_type(8)));
typedef __bf16 bf16x4 __attribute__((ext_vector_type(4)));
typedef float f32x4 __attribute__((ext_vector_type(4)));

#define AS1 __attribute__((address_space(1)))
#define AS3 __attribute__((address_space(3)))

// B=4, S=256, H=12, DH=64(pad 128), D=768, FD=2048, FU=2048
// R29 (this round): REVERT R28 B-direct (153us: L2 latency on critical path).
// fp2's 105us = LDS 2304cyc + MFMA 2483cyc PER STEP, fully serialized: at
// each barrier all 8 waves dump 24 ds_reads at once; fair arbitration makes
// every wave's reads finish ~simultaneously -> nobody MFMAs early. Fix =
// quarter-split the step (reads Q_{i+1} interleaved with MFMA Q_i) pinned by
// compile-time sched_barrier(0) (NO runtime barriers - R25's mistake) +
// setprio(1) around MFMA clusters (T5 pays once phases create role split).

__device__ __forceinline__ void gld16(const bf16* g, bf16* l) {
  __builtin_amdgcn_global_load_lds((AS1 void*)g, (AS3 void*)l, 16, 0, 0);
}

__global__ void k_sentinel(float* __restrict__ out) {
  int i = blockIdx.x * 256 + threadIdx.x;
  if (i < 2097152) out[i] = 1048576.0f;
}

// ---------------- merged elementwise prep ----------------
// sections (256-thr blocks): s0 invln[1], s1 encWb[1536], s2 probsT[3072],
// s3 maskb[4096], s4 WOb[1152], s5 Xb[768], s6 BgTail[1536]  -> 12161 blocks
__global__ void k_prep(const float* __restrict__ lns, float* __restrict__ invln,
                       const float* __restrict__ enc_W, bf16* __restrict__ encWb,
                       const float* __restrict__ probs, bf16* __restrict__ probsT,
                       const int* __restrict__ cmask, bf16* __restrict__ maskb,
                       const float* __restrict__ W_O, bf16* __restrict__ WOb,
                       const float* __restrict__ resid, bf16* __restrict__ Xb,
                       bf16* __restrict__ BgTail, long ldTail) {
  const int bid = blockIdx.x, t = threadIdx.x;
  if (bid < 1) {                                  // s0: invln (1024)
    for (int k = 0; k < 4; k++) { int j = t + k * 256; invln[j] = 1.0f / lns[j]; }
  } else if (bid < 1537) {                        // s1: encWb cast (393216 v4)
    long idx = ((long)(bid - 1) * 256 + t) * 4;
    float4 v = *(const float4*)(enc_W + idx);
    bf16x4 o; o[0]=(bf16)v.x; o[1]=(bf16)v.y; o[2]=(bf16)v.z; o[3]=(bf16)v.w;
    *(bf16x4*)(encWb + idx) = o;
  } else if (bid < 4609) {                        // s2: probsT (786432 v4)
    long idx = ((long)(bid - 1537) * 256 + t) * 4;
    int s = (int)(idx & 255), q = (int)((idx >> 8) & 255);
    int hb = (int)(idx >> 16), h = hb % 12, b = hb / 12;
    float4 v = *(const float4*)(probs + idx);
    bf16x4 o; o[0]=(bf16)v.x; o[1]=(bf16)v.y; o[2]=(bf16)v.z; o[3]=(bf16)v.w;
    *(bf16x4*)(probsT + (long)b * 786432 + (long)q * 3072 + h * 256 + s) = o;
  } else if (bid < 8705) {                        // s3: maskb (1048576 v4)
    long idx = ((long)(bid - 4609) * 256 + t) * 4;
    int4 v = *(const int4*)(cmask + idx);
    bf16x4 o; o[0]=(bf16)(float)v.x; o[1]=(bf16)(float)v.y;
    o[2]=(bf16)(float)v.z; o[3]=(bf16)(float)v.w;
    *(bf16x4*)(maskb + idx) = o;
  } else if (bid < 9857) {                        // s4: WOb (294912 v4)
    long idx = ((long)(bid - 8705) * 256 + t) * 4;
    int o = (int)(idx % 768), r = (int)((idx / 768) & 127), h = (int)(idx / (768 * 128));
    bf16x4 ov;
    if (r < 64) {
      float4 v = *(const float4*)(W_O + (long)(h * 64 + r) * 768 + o);
      ov[0]=(bf16)v.x; ov[1]=(bf16)v.y; ov[2]=(bf16)v.z; ov[3]=(bf16)v.w;
    } else { ov[0]=ov[1]=ov[2]=ov[3]=(bf16)0.0f; }
    *(bf16x4*)(WOb + idx) = ov;
  } else if (bid < 10625) {                       // s5: Xb (196608 v4)
    long idx = ((long)(bid - 9857) * 256 + t) * 4;
    float il = 1.0f / lns[idx / 768];
    float4 v = *(const float4*)(resid + idx);
    bf16x4 o; o[0]=(bf16)(v.x*il); o[1]=(bf16)(v.y*il);
    o[2]=(bf16)(v.z*il); o[3]=(bf16)(v.w*il);
    *(bf16x4*)(Xb + idx) = o;
  } else {                                        // s6: B_g K-tail (393216 v4)
    long idx = ((long)(bid - 10625) * 256 + t) * 4;
    int f = (int)(idx / 768), d = (int)(idx % 768);
    float4 v = *(const float4*)(enc_W + idx);
    bf16x4 o; o[0]=(bf16)v.x; o[1]=(bf16)v.y; o[2]=(bf16)v.z; o[3]=(bf16)v.w;
    *(bf16x4*)(BgTail + (long)f * ldTail + d) = o;
  }
}

// ---------------- merged tiled transposes ----------------
// zones: WVt[1152] WOt[576] updWt[1536] Ut[2048] -> 5312 blocks
__global__ void k_prepT(const float* __restrict__ wv, bf16* __restrict__ WVt,
                        const float* __restrict__ wo, bf16* __restrict__ W_Ot,
                        const float* __restrict__ updW, bf16* __restrict__ updWt,
                        const float* __restrict__ pr, const float* __restrict__ lns,
                        bf16* __restrict__ Ut) {
  __shared__ float tile[32][33];
  const int bid = blockIdx.x;
  int lane = threadIdx.x & 31, rg = threadIdx.x >> 5;
  if (bid < 1152) {                 // WVt[h][k<128][i<768] = W_V[h,i,k]
    int r0 = bid;
    int x = r0 % 4, y = (r0 / 4) % 24, h = r0 / 96;
    int k0 = x * 32, i0 = y * 32;
    if (k0 < 64) {
      for (int r = rg; r < 32; r += 8)
        tile[r][lane] = wv[((long)(h * 768 + i0 + r)) * 64 + k0 + lane];
      __syncthreads();
      for (int r = rg; r < 32; r += 8)
        WVt[((long)h * 128 + k0 + r) * 768 + i0 + lane] = (bf16)tile[lane][r];
    } else {
      for (int r = rg; r < 32; r += 8)
        WVt[((long)h * 128 + k0 + r) * 768 + i0 + lane] = (bf16)0.0f;
    }
  } else if (bid < 1728) {          // W_Ot[h][o][k64] = W_O[h,k,o]
    int r0 = bid - 1152;
    int x = r0 % 2, y = (r0 / 2) % 24, h = r0 / 48;
    int k0 = x * 32, o0 = y * 32;
    for (int r = rg; r < 32; r += 8)
      tile[r][lane] = wo[((long)(h * 64 + k0 + r)) * 768 + o0 + lane];
    __syncthreads();
    for (int r = rg; r < 32; r += 8)
      W_Ot[((long)(h * 768 + o0 + r)) * 64 + k0 + lane] = (bf16)tile[lane][r];
  } else if (bid < 3264) {          // updWt[u][i] = up_dec_W[i][u]
    int r0 = bid - 1728;
    int u0 = (r0 % 64) * 32, i0 = (r0 / 64) * 32;
    for (int r = rg; r < 32; r += 8)
      tile[r][lane] = updW[((long)(i0 + r)) * 2048 + u0 + lane];
    __syncthreads();
    for (int r = rg; r < 32; r += 8)
      updWt[((long)(u0 + r)) * 768 + i0 + lane] = (bf16)tile[lane][r];
  } else {                          // Ut[b][u][s] = pruned[b,s,u]/ln
    int r0 = bid - 3264;
    int u0 = (r0 % 64) * 32, s0 = ((r0 / 64) % 8) * 32, b = r0 / 512;
    for (int r = rg; r < 32; r += 8) {
      int s = s0 + r;
      tile[r][lane] = pr[((long)(b * 256 + s)) * 2048 + u0 + lane] *
                      (1.0f / lns[b * 256 + s]);
    }
    __syncthreads();
    for (int r = rg; r < 32; r += 8)
      Ut[((long)b * 2048 + u0 + r) * 256 + s0 + lane] = (bf16)tile[lane][r];
  }
}

// reduce 4 fp32 split-K slabs of S and cast into the bf16 A_g K-tail
__global__ void k_sred(const float* __restrict__ Sp, bf16* __restrict__ dst, long ldd) {
  int i = blockIdx.x * 256 + threadIdx.x;   // 196608 vec4s
  if (i < 196608) {
    long idx = (long)i * 4;
    int m = (int)(idx / 768), o = (int)(idx % 768);
    float4 v = *(const float4*)(Sp + idx);
    float4 a = *(const float4*)(Sp + 786432 + idx);
    float4 b = *(const float4*)(Sp + 2 * 786432 + idx);
    float4 c = *(const float4*)(Sp + 3 * 786432 + idx);
    v.x += a.x + b.x + c.x; v.y += a.y + b.y + c.y;
    v.z += a.z + b.z + c.z; v.w += a.w + b.w + c.w;
    bf16x4 ov;
    ov[0] = (bf16)v.x; ov[1] = (bf16)v.y; ov[2] = (bf16)v.z; ov[3] = (bf16)v.w;
    *(bf16x4*)(dst + (long)m * ldd + o) = ov;
  }
}

// ---------------- bias chain (fp32, block-parallel) ----------------

__device__ __forceinline__ float blk_reduce(float s) {
  __shared__ float red[256];
  red[threadIdx.x] = s; __syncthreads();
  for (int o = 128; o > 0; o >>= 1) {
    if ((int)threadIdx.x < o) red[threadIdx.x] += red[threadIdx.x + o];
    __syncthreads();
  }
  float r = red[0]; __syncthreads();
  return r;
}

__global__ void k_bias_t(const float* __restrict__ W_V, const float* __restrict__ up_b,
                         float* __restrict__ t_hk) {
  int j = blockIdx.x, h = j >> 6, k = j & 63;
  float s = 0.f;
  for (int m = threadIdx.x; m < 768; m += 256)
    s += W_V[((long)(h * 768 + m)) * 64 + k] * up_b[m];
  float r = blk_reduce(s);
  if (threadIdx.x == 0) t_hk[j] = r;
}

__global__ void k_bias_w(const float* __restrict__ W_O, const float* __restrict__ t_hk,
                         float* __restrict__ w) {
  int d = blockIdx.x;
  float s = 0.f;
  for (int j = threadIdx.x; j < 768; j += 256)
    s += W_O[(long)j * 768 + d] * t_hk[j];
  float r = blk_reduce(s);
  if (threadIdx.x == 0) w[d] = r;
}

__global__ void k_bias_c(const float* __restrict__ enc_W, const float* __restrict__ enc_b,
                         const float* __restrict__ b_dec, const float* __restrict__ w,
                         float* __restrict__ c0, float* __restrict__ c1) {
  int f = blockIdx.x;
  float s0 = 0.f, s1 = 0.f;
  for (int d = threadIdx.x; d < 768; d += 256) {
    float e = enc_W[(long)f * 768 + d];
    s0 += e * b_dec[d];
    s1 += e * w[d];
  }
  float r0 = blk_reduce(s0);
  float r1 = blk_reduce(s1);
  if (threadIdx.x == 0) { c0[f] = enc_b[f] - r0; c1[f] = r1; }
}

// ---------------- GEMM (BT form: C[m,n] = sum_k A[m,k]*B[n,k]) ----------------
// BK=64, XOR-swizzled staging. K (and kChunk) must be multiples of 64.
// mode 0: bf16 store; mode 1: *= bf16 mask, bf16 store;
// mode 2: split-K fp32 overwrite; mode 3: split-K fp32 read-accumulate;
// mode 4: batched split-K fp32 overwrite (z = bb*batchH + kc, batchH = #kc)
__global__ __launch_bounds__(256)
void gemm_bt(const bf16* __restrict__ A, const bf16* __restrict__ B, void* __restrict__ Cv,
             int M, int N, int K,
             long lda, long ldb, long ldc,
             int batchH,
             long sa_b, long sa_h, long sb_b, long sb_h, long sc_b, long sc_h,
             int mode, int kChunk,
             const bf16* __restrict__ mask, long mask_ld)
{
  __shared__ __align__(16) bf16 Asm[128 * 64];
  __shared__ __align__(16) bf16 Bsm[128 * 64];

  const int t = threadIdx.x;

  // bijective XCD-aware remap of the (x,y) tile id (m204 formula)
  const int nbx = gridDim.x, nby = gridDim.y;
  const int nxy = nbx * nby;
  int orig = blockIdx.x + nbx * blockIdx.y;
  int qq = nxy >> 3, rr = nxy & 7;
  int xcd = orig & 7, lid = orig >> 3;
  int swz = (xcd < rr) ? (xcd * (qq + 1) + lid)
                       : (rr * (qq + 1) + (xcd - rr) * qq + lid);
  const int m0 = (swz % nby) * 128;
  const int n0 = (swz / nby) * 128;

  long aoff, boff, coff;
  int k0, k1;
  if (mode == 4) {
    int z = blockIdx.z;
    int bb = z / batchH, kc = z - bb * batchH;
    aoff = (long)bb * sa_b;
    boff = (long)bb * sb_b;
    coff = (long)bb * sc_b + (long)kc * sc_h;
    k0 = kc * kChunk; k1 = k0 + kChunk; if (k1 > K) k1 = K;
  } else if (mode >= 2) {
    int z = blockIdx.z;
    aoff = 0; boff = 0;
    coff = (long)z * (long)M * ldc;
    k0 = z * kChunk; k1 = k0 + kChunk; if (k1 > K) k1 = K;
  } else {
    int z = blockIdx.z;
    int bb = z / batchH, hh = z - bb * batchH;
    aoff = (long)bb * sa_b + (long)hh * sa_h;
    boff = (long)bb * sb_b + (long)hh * sb_h;
    coff = (long)bb * sc_b + (long)hh * sc_h;
    k0 = 0; k1 = K;
  }

  const bf16* Ab = A + aoff + (long)m0 * lda;
  const bf16* Bb = B + boff + (long)n0 * ldb;

  const int r0 = t >> 3;           // 0..31 (staging row within 32-row group)
  const int g8 = t & 7;            // staging col-group (LDS slot)

  const int L = t & 63, w = t >> 6;
  const int wm = (w & 1) * 64, wn = (w >> 1) * 64;
  const int r16 = L & 15, q = L >> 4;

  f32x4 acc[4][4];
#pragma unroll
  for (int i = 0; i < 4; i++)
#pragma unroll
    for (int j = 0; j < 4; j++) acc[i][j] = (f32x4){0.f, 0.f, 0.f, 0.f};

  for (int kt = k0; kt < k1; kt += 64) {
#pragma unroll
    for (int j = 0; j < 4; j++) {
      int row = j * 32 + r0;
      int sc = ((g8 ^ (row & 7)) << 3);      // source col swizzle
      gld16(Ab + (long)row * lda + (kt + sc), &Asm[j * 2048 + t * 8]);
      gld16(Bb + (long)row * ldb + (kt + sc), &Bsm[j * 2048 + t * 8]);
    }
    __syncthreads();

#pragma unroll
    for (int h2 = 0; h2 < 2; h2++) {
      bf16x8 af[4], bfr[4];
#pragma unroll
      for (int i = 0; i < 4; i++) {
        int ra = wm + i * 16 + r16;
        af[i]  = *(const bf16x8*)&Asm[ra * 64 + ((((h2 << 2) + q) ^ (ra & 7)) << 3)];
        int rb = wn + i * 16 + r16;
        bfr[i] = *(const bf16x8*)&Bsm[rb * 64 + ((((h2 << 2) + q) ^ (rb & 7)) << 3)];
      }
#pragma unroll
      for (int mi = 0; mi < 4; mi++)
#pragma unroll
        for (int ni = 0; ni < 4; ni++)
          acc[mi][ni] = __builtin_amdgcn_mfma_f32_16x16x32_bf16(af[mi], bfr[ni], acc[mi][ni], 0, 0, 0);
    }
    __syncthreads();
  }

  if (mode >= 2) {
    float* C = (float*)Cv;
#pragma unroll
    for (int mi = 0; mi < 4; mi++)
#pragma unroll
      for (int ni = 0; ni < 4; ni++)
#pragma unroll
        for (int r = 0; r < 4; r++) {
          int gm = m0 + wm + mi * 16 + q * 4 + r;
          int gn = n0 + wn + ni * 16 + r16;
          long idx = coff + (long)gm * ldc + gn;
          float v = acc[mi][ni][r];
          if (mode == 3) v += C[idx];
          C[idx] = v;
        }
  } else {
    bf16* C = (bf16*)Cv;
#pragma unroll
    for (int mi = 0; mi < 4; mi++)
#pragma unroll
      for (int ni = 0; ni < 4; ni++)
#pragma unroll
        for (int r = 0; r < 4; r++) {
          int gm = m0 + wm + mi * 16 + q * 4 + r;
          int gn = n0 + wn + ni * 16 + r16;
          float v = acc[mi][ni][r];
          if (mode == 1) v *= (float)mask[(long)gm * mask_ld + gn];
          C[coff + (long)gm * ldc + gn] = (bf16)v;
        }
  }
}

// ------------- 256x256-tile split-K GEMM (final GEMM) ------------------------
// C[m,n] (+)= sum_k A[m,k]*B[n,k], fp32 C. 512 threads = 8 waves (2M x 4N),
// per-wave 128x64 output. BK=64. 2 LDS buffers (128 KiB), depth-1 prefetch,
// counted vmcnt(8) (0 only at epilogue), 2 runtime barriers per K-step.
// K-step body is QUARTER-SPLIT: reads for quarter i+1 are issued between the
// MFMA clusters of quarter i, pinned with compile-time sched_barrier(0) (no
// runtime syncs) so each wave's 24 ds_reads smear through the step instead of
// all hitting the LDS port at the barrier (R26-R28: LDS 2304cyc + MFMA
// 2483cyc executed as SUM because every wave's reads completed together).
// setprio(1) around MFMA clusters (T5: pays once phases create role split).
// Work remap: z = fid % nz -> one K-slab per XCD (R24: FETCH 253->76MB).
// K, kChunk multiples of 64. mode 2 = overwrite, 3 = read-accumulate.
__global__ __launch_bounds__(512, 2)
void gemm_fp2(const bf16* __restrict__ A, const bf16* __restrict__ B,
              float* __restrict__ C,
              int M, int N, int K, long lda, long ldb, long ldc,
              int mode, int kChunk)
{
  __shared__ __align__(16) bf16 SM[2][2][16384];   // [buf][A|B][256*64]

  const int t = threadIdx.x;

  const int nz = gridDim.z;
  int fid = blockIdx.x + gridDim.x * (blockIdx.y + gridDim.y * blockIdx.z);
  const int z  = fid % nz;                 // K-slab, constant per XCD when nz=8
  const int t2 = fid / nz;                 // 0..31 (m,n)-tile within the slab
  const int m0 = (t2 >> 3) * 256;          // 4 m-tiles
  const int n0 = (t2 & 7) * 256;           // 8 n-tiles

  const long coff = (long)z * (long)M * ldc;
  int k0 = z * kChunk, k1 = k0 + kChunk; if (k1 > K) k1 = K;
  const int NT = (k1 > k0) ? (k1 - k0) >> 6 : 0;

  const bf16* Ab = A + (long)m0 * lda + k0;
  const bf16* Bb = B + (long)n0 * ldb + k0;

  const int sr = t >> 3;           // 0..63 staging row within 64-row group
  const int g8 = t & 7;            // staging col-group (LDS slot)

  const int L = t & 63, w = t >> 6;          // 8 waves
  const int wm = (w & 1) * 128;              // 2 waves over M (256)
  const int wn = (w >> 1) * 64;              // 4 waves over N (256)
  const int r16 = L & 15, q = L >> 4;

  f32x4 acc[8][4];
#pragma unroll
  for (int i = 0; i < 8; i++)
#pragma unroll
    for (int j = 0; j < 4; j++) acc[i][j] = (f32x4){0.f, 0.f, 0.f, 0.f};

  // stage K-tile tt into buffer buf: 8 gld16 per thread (4 A rounds, 4 B)
  auto stage = [&](int tt, int buf) {
    const bf16* Ap = Ab + (long)tt * 64;
    const bf16* Bp = Bb + (long)tt * 64;
#pragma unroll
    for (int j = 0; j < 4; j++) {
      int row = j * 64 + sr;
      int sc = ((g8 ^ (row & 7)) << 3);
      gld16(Ap + (long)row * lda + sc, &SM[buf][0][j * 4096 + t * 8]);
    }
#pragma unroll
    for (int j = 0; j < 4; j++) {
      int row = j * 64 + sr;
      int sc = ((g8 ^ (row & 7)) << 3);
      gld16(Bp + (long)row * ldb + sc, &SM[buf][1][j * 4096 + t * 8]);
    }
  };

  if (NT >= 1) stage(0, 0);

  for (int tt = 0; tt < NT; tt++) {
    if (tt + 1 < NT) {
      stage(tt + 1, (tt + 1) & 1);           // prefetch next into other buffer
      asm volatile("s_waitcnt vmcnt(8)" ::: "memory");   // stage(tt) done
    } else {
      asm volatile("s_waitcnt vmcnt(0)" ::: "memory");   // epilogue drain
    }
    __builtin_amdgcn_s_barrier();            // buffer tt&1 ready for all waves

    const bf16* As = &SM[tt & 1][0][0];
    const bf16* Bs = &SM[tt & 1][1][0];

    bf16x8 a0[4], a1[4], bq0[4], bq1[4];
    // ---- Q0 reads: A mi0-3 (h2=0) + B (h2=0); Q1 reads: A mi4-7 (h2=0)
#pragma unroll
    for (int i = 0; i < 4; i++) {
      int ra = wm + i * 16 + r16;
      a0[i] = *(const bf16x8*)&As[ra * 64 + ((q ^ (ra & 7)) << 3)];
    }
#pragma unroll
    for (int i = 0; i < 4; i++) {
      int rb = wn + i * 16 + r16;
      bq0[i] = *(const bf16x8*)&Bs[rb * 64 + ((q ^ (rb & 7)) << 3)];
    }
#pragma unroll
    for (int i = 0; i < 4; i++) {
      int ra = wm + (4 + i) * 16 + r16;
      a1[i] = *(const bf16x8*)&As[ra * 64 + ((q ^ (ra & 7)) << 3)];
    }
    __builtin_amdgcn_sched_barrier(0);
    // ---- MFMA Q0: mi0-3 x h2=0
    __builtin_amdgcn_s_setprio(1);
#pragma unroll
    for (int mi = 0; mi < 4; mi++)
#pragma unroll
      for (int ni = 0; ni < 4; ni++)
        acc[mi][ni] = __builtin_amdgcn_mfma_f32_16x16x32_bf16(a0[mi], bq0[ni], acc[mi][ni], 0, 0, 0);
    __builtin_amdgcn_s_setprio(0);
    // ---- Q2 reads: A mi0-3 (h2=1, reuse a0) + B (h2=1)
#pragma unroll
    for (int i = 0; i < 4; i++) {
      int ra = wm + i * 16 + r16;
      a0[i] = *(const bf16x8*)&As[ra * 64 + (((4 + q) ^ (ra & 7)) << 3)];
    }
#pragma unroll
    for (int i = 0; i < 4; i++) {
      int rb = wn + i * 16 + r16;
      bq1[i] = *(const bf16x8*)&Bs[rb * 64 + (((4 + q) ^ (rb & 7)) << 3)];
    }
    __builtin_amdgcn_sched_barrier(0);
    // ---- MFMA Q1: mi4-7 x h2=0
    __builtin_amdgcn_s_setprio(1);
#pragma unroll
    for (int mi = 0; mi < 4; mi++)
#pragma unroll
      for (int ni = 0; ni < 4; ni++)
        acc[4 + mi][ni] = __builtin_amdgcn_mfma_f32_16x16x32_bf16(a1[mi], bq0[ni], acc[4 + mi][ni], 0, 0, 0);
    __builtin_amdgcn_s_setprio(0);
    // ---- Q3 reads: A mi4-7 (h2=1, reuse a1)
#pragma unroll
    for (int i = 0; i < 4; i++) {
      int ra = wm + (4 + i) * 16 + r16;
      a1[i] = *(const bf16x8*)&As[ra * 64 + (((4 + q) ^ (ra & 7)) << 3)];
    }
    __builtin_amdgcn_sched_barrier(0);
    // ---- MFMA Q2: mi0-3 x h2=1
    __builtin_amdgcn_s_setprio(1);
#pragma unroll
    for (int mi = 0; mi < 4; mi++)
#pragma unroll
      for (int ni = 0; ni < 4; ni++)
        acc[mi][ni] = __builtin_amdgcn_mfma_f32_16x16x32_bf16(a0[mi], bq1[ni], acc[mi][ni], 0, 0, 0);
    __builtin_amdgcn_s_setprio(0);
    __builtin_amdgcn_sched_barrier(0);
    // ---- MFMA Q3: mi4-7 x h2=1
    __builtin_amdgcn_s_setprio(1);
#pragma unroll
    for (int mi = 0; mi < 4; mi++)
#pragma unroll
      for (int ni = 0; ni < 4; ni++)
        acc[4 + mi][ni] = __builtin_amdgcn_mfma_f32_16x16x32_bf16(a1[mi], bq1[ni], acc[4 + mi][ni], 0, 0, 0);
    __builtin_amdgcn_s_setprio(0);

    __builtin_amdgcn_s_barrier();            // all waves done reading buf tt&1
  }

#pragma unroll
  for (int mi = 0; mi < 8; mi++)
#pragma unroll
    for (int ni = 0; ni < 4; ni++)
#pragma unroll
      for (int r = 0; r < 4; r++) {
        int gm = m0 + wm + mi * 16 + q * 4 + r;
        int gn = n0 + wn + ni * 16 + r16;
        long idx = coff + (long)gm * ldc + gn;
        float v = acc[mi][ni][r];
        if (mode == 3) v += C[idx];
        C[idx] = v;
      }
}

// ---------------- final reduce + bias epilogue (fp32 out, float4) ------------
__global__ void k_out(const float* __restrict__ Cp, const float* __restrict__ c0,
                      const float* __restrict__ c1, const float* __restrict__ invln,
                      float* __restrict__ out, int nsplit) {
  int i4 = blockIdx.x * 256 + threadIdx.x;          // 524288
  long i = (long)i4 * 4;
  int n = (int)(i & 2047), m = (int)(i >> 11);
  float4 v = *(const float4*)(Cp + i);
  for (int z = 1; z < nsplit; z++) {
    float4 u = *(const float4*)(Cp + i + (long)z * 2097152);
    v.x += u.x; v.y += u.y; v.z += u.z; v.w += u.w;
  }
  float il = invln[m];
  float4 a = *(const float4*)(c0 + n);
  float4 b = *(const float4*)(c1 + n);
  v.x += a.x + b.x * il;
  v.y += a.y + b.y * il;
  v.z += a.z + b.z * il;
  v.w += a.w + b.w * il;
  *(float4*)(out + i) = v;
}

// ---------------- host ----------------

extern "C" void kernel_launch(void* const* d_in, const int* in_sizes, int n_in,
                              void* d_out, int out_size, void* d_ws, size_t ws_size,
                              hipStream_t stream) {
  (void)out_size;
  float* out = (float*)d_out;

  // ---- resolve inputs by size (order-agnostic) ----
  int iresid = -1, iln = -1, iprobs = -1, iencb = -1, ipruned = -1, imask = -1;
  int iwo = -1, iwv = -1, iencw = -1, iupdw = -1, ibdec = -1, iupb = -1;
  for (int i = 0; i < n_in; i++) {
    switch (in_sizes[i]) {
      case 786432:  iresid  = i; break;
      case 1024:    iln     = i; break;
      case 3145728: iprobs  = i; break;
      case 2048:    iencb   = i; break;
      case 2097152: ipruned = i; break;
      case 4194304: imask   = i; break;
      case 589824:  if (iwo   < 0) iwo   = i; else iwv   = i; break;
      case 1572864: if (iencw < 0) iencw = i; else iupdw = i; break;
      case 768:     if (ibdec < 0) ibdec = i; else iupb  = i; break;
      default: break;
    }
  }
  bool ok = n_in == 12 && iresid >= 0 && iln >= 0 && iprobs >= 0 && iencb >= 0 &&
            ipruned >= 0 && imask >= 0 && iwo >= 0 && iwv >= 0 && iencw >= 0 &&
            iupdw >= 0 && ibdec >= 0 && iupb >= 0;
  if (!ok) { k_sentinel<<<8192, 256, 0, stream>>>(out); return; }

  const float* resid = (const float*)d_in[iresid];
  const float* lns   = (const float*)d_in[iln];
  const float* probs = (const float*)d_in[iprobs];
  const float* W_O   = (const float*)d_in[iwo];
  const float* W_V   = (const float*)d_in[iwv];
  const float* enc_W = (const float*)d_in[iencw];
  const float* enc_b = (const float*)d_in[iencb];
  const float* b_dec = (const float*)d_in[ibdec];
  const float* updW  = (const float*)d_in[iupdw];
  const float* up_b  = (const float*)d_in[iupb];
  const float* pruned= (const float*)d_in[ipruned];
  const int*   cmask = (const int*)d_in[imask];

  // ---- workspace sizing ----
  auto pad = [](size_t b) -> size_t { return (b + 255) & ~(size_t)255; };
  const size_t prepB = pad(2359296) + pad(2359296) + pad(3145728) + pad(1572864) +
                       pad(3145728) + pad(1179648) + pad(3145728) + pad(18874368) +
                       pad(12582912);
  const size_t persB = pad(6291456) + pad(4194304) + pad(6291456) + pad(6291456) +
                       pad(8388608) + pad(4096) + pad(3072) + pad(3072) +
                       pad(8192) + pad(8192);
  auto needB = [&](int g, int ns) -> size_t {
    size_t cp = (size_t)ns * 8388608;
    size_t ov = prepB > cp ? prepB : cp;
    long KA = (long)g * 2048 + 768;
    size_t ab = pad((size_t)1024 * KA * 2) + pad((size_t)2048 * KA * 2);
    return ov + persB + ab + (2ull << 20);   // 2MiB slack
  };
  // prefer gs=12 (one final GEMM) + nsplit=8 (grid (8,4,8)=256 blocks = 1/CU)
  const int cgs[14] = {12, 12, 12, 6, 6, 4, 3, 2, 2, 1, 1, 1, 1, 1};
  const int cns[14] = { 8,  4, 2, 8, 4, 4, 4, 4, 2, 8, 4, 2, 2, 1};
  int gs = 0, nsplit = 0;
  for (int ci = 0; ci < 14; ci++) {
    if (needB(cgs[ci], cns[ci]) <= ws_size) { gs = cgs[ci]; nsplit = cns[ci]; break; }
  }
  if (gs == 0) { gs = 1; nsplit = 1; }

  const long KA = (long)gs * 2048 + 768;     // A_g/B_g leading dim (K incl. tail)

  char* p = (char*)d_ws;
  auto alloc = [&](size_t bytes) -> char* {
    char* r = p; p += (bytes + 255) & ~(size_t)255; return r;
  };
  // -- overlay region: prep buffers, later reused as Cpart --
  char* overlayBase = p;
  bf16*  WOb    = (bf16*)alloc(12ull * 128 * 768 * 2);
  bf16*  WVt    = (bf16*)alloc(12ull * 128 * 768 * 2);
  bf16*  updWt  = (bf16*)alloc(2048ull * 768 * 2);
  bf16*  Xb     = (bf16*)alloc(1024ull * 768 * 2);
  bf16*  encWb  = (bf16*)alloc(2048ull * 768 * 2);
  bf16*  W_Ot   = (bf16*)alloc(12ull * 768 * 64 * 2);
  bf16*  T1     = (bf16*)alloc(12ull * 1024 * 128 * 2);
  bf16*  T3     = (bf16*)alloc(4ull * 768 * 3072 * 2);
  float* Sp     = (float*)alloc(4ull * 1024 * 768 * 4);
  {
    size_t used = (size_t)(p - overlayBase);
    size_t cp = (size_t)nsplit * 8388608;
    p = overlayBase + (used > cp ? used : cp);
  }
  float* Cpart  = (float*)overlayBase;       // aliases dead prep buffers
  // -- persistent region --
  bf16*  G_t    = (bf16*)alloc(12ull * 2048 * 128 * 2);
  bf16*  Ut     = (bf16*)alloc(4ull * 2048 * 256 * 2);
  bf16*  E1     = (bf16*)alloc(12ull * 2048 * 128 * 2);
  bf16*  probsT = (bf16*)alloc(4ull * 256 * 3072 * 2);
  bf16*  maskb  = (bf16*)alloc(2048ull * 2048 * 2);
  float* invln  = (float*)alloc(1024 * 4);
  float* t_hk   = (float*)alloc(768 * 4);
  float* wv     = (float*)alloc(768 * 4);
  float* c0     = (float*)alloc(2048 * 4);
  float* c1     = (float*)alloc(2048 * 4);
  bf16*  A_g    = (bf16*)alloc((size_t)1024 * KA * 2);
  bf16*  B_g    = (bf16*)alloc((size_t)2048 * KA * 2);

  // ---- prep (2 merged kernels + bias chain) ----
  k_prep<<<12161, 256, 0, stream>>>(lns, invln, enc_W, encWb, probs, probsT,
                                    cmask, maskb, W_O, WOb, resid, Xb,
                                    B_g + (long)gs * 2048, KA);
  k_prepT<<<5312, 256, 0, stream>>>(W_V, WVt, W_O, W_Ot, updW, updWt,
                                    pruned, lns, Ut);
  k_bias_t<<<768, 256, 0, stream>>>(W_V, up_b, t_hk);
  k_bias_w<<<768, 256, 0, stream>>>(W_O, t_hk, wv);
  k_bias_c<<<2048, 256, 0, stream>>>(enc_W, enc_b, b_dec, wv, c0, c1);

  // Merged E1 + G_t (z = 24, bb selects the problem via pointer-diff strides):
  //   bb=0: E1[h][f][k]  = encWb[f,o] . WOb[h][k][o]
  //   bb=1: G_t[h][u][k] = updWt[u,i] . WVt[h][k][i]
  gemm_bt<<<dim3(1, 16, 24), 256, 0, stream>>>(
      encWb, WOb, E1, 2048, 128, 768,
      768, 768, 128, 12,
      (long)(updWt - encWb), 0,
      (long)(WVt - WOb), (long)128 * 768,
      (long)(G_t - E1), (long)2048 * 128,
      0, 0, nullptr, 0);

  // ---- init path: T1 -> T3 -> S (split-K) -> reduce into A_g K-tail ----
  // T1[h][bs][k128] = Xb[bs,i] . WVt[h][k][i]   M=1024 N=128 K=768 (z=h)
  gemm_bt<<<dim3(1, 8, 12), 256, 0, stream>>>(
      Xb, WVt, T1, 1024, 128, 768,
      768, 768, 128, 12,
      0, 0, 0, (long)128 * 768, 0, (long)1024 * 128,
      0, 0, nullptr, 0);

  // T3[b][o][h*256+s] = W_Ot[h][o][k] . T1[h][b*256+s][k]   M=768 N=256 K=64
  gemm_bt<<<dim3(2, 6, 48), 256, 0, stream>>>(
      W_Ot, T1, T3, 768, 256, 64,
      64, 128, 3072, 12,
      0, (long)768 * 64, (long)256 * 128, (long)1024 * 128, 2359296, 256,
      0, 0, nullptr, 0);

  // S (mode 4, batched split-K): 16 z-blocks, kChunk=768 -> 12 K-steps each.
  gemm_bt<<<dim3(6, 2, 16), 256, 0, stream>>>(
      probsT, T3, Sp, 256, 768, 3072,
      3072, 3072, 768, 4,
      786432, 0, 2359296, 0, 196608, 786432,
      4, 768, nullptr, 0);

  // reduce 4 Sp slabs + cast -> A_g[:, gs*2048 .. +768]
  k_sred<<<768, 256, 0, stream>>>(Sp, A_g + (long)gs * 2048, KA);

  // ---- head-group loop (single iteration when gs==12) ----
  for (int g = 0; g < 12 / gs; g++) {
    // V_g: B_g[f][hh*2048+u] = maskb[f,u] * (E1_h[f,k] . G_t_h[u,k])  K=64
    gemm_bt<<<dim3(16, 16, gs), 256, 0, stream>>>(
        E1 + (long)g * gs * 2048 * 128, G_t + (long)g * gs * 2048 * 128, B_g,
        2048, 2048, 64,
        128, 128, KA, gs,
        0, (long)2048 * 128, 0, (long)2048 * 128, 0, 2048,
        1, 0, maskb, 2048);

    // PU_g: A_g[b*256+q][hh*2048+u] = probsT[b][q][(g*gs+hh)*256 + s] . Ut[b][u][s]
    gemm_bt<<<dim3(16, 2, 4 * gs), 256, 0, stream>>>(
        probsT + (long)g * gs * 256, Ut, A_g,
        256, 2048, 256,
        3072, 256, KA, gs,
        786432, 256, (long)2048 * 256, 0, 256 * KA, 2048,
        0, 0, nullptr, 0);

    // Cpart (+)= A_g[bq,k] . B_g[f,k]  -- 256x256-tile, quarter-split schedule
    int Kthis = (g == 0) ? (int)KA : gs * 2048;
    int kc = ((Kthis / nsplit + 63) / 64) * 64;
    gemm_fp2<<<dim3(8, 4, nsplit), 512, 0, stream>>>(
        A_g, B_g, Cpart,
        1024, 2048, Kthis,
        KA, KA, 2048,
        (g == 0) ? 2 : 3, kc);
  }

  // out[b,q,f] = fp32( sum_z Cpart + c0[f] + c1[f]*invln[bq] )
  k_out<<<2048, 256, 0, stream>>>(Cpart, c0, c1, invln, out, nsplit);
}

// Round 11
// 406.698 us; speedup vs baseline: 1.1832x; 1.0732x over previous
//
#include <hip/hip_runtime.h>
#include <hip/hip_bf16.h>
#include <stdint.h>

typedef __bf16 bf16;
typedef __bf16 bf16x8 __attribute__((ext_vector_type(8)));
typedef __bf16 bf16x4 __attribute__((ext_vector_type(4)));
typedef float f32x4 __attribute__((ext_vector_type(4)));

#define AS1 __attribute__((address_space(1)))
#define AS3 __attribute__((address_space(3)))

// B=4, S=256, H=12, DH=64(pad 128), D=768, FD=2048, FU=2048
// R30 (this round):
//  - REVERT R29 quarter-split (null: 107.4 vs 105.0; 4th schedule experiment
//    within +-10% -> final GEMM locked at ~105us, stop touching it).
//  - Non-final time ~330us across 13 dispatches is now the target. gemm_bt's
//    bf16 epilogue was 64 scalar 2B stores (+64 scalar mask loads in mode 1)
//    per thread = up to 32K scalar mem ops per block (V_g: 3072 blocks).
//    New LDS-bounce epilogue (modes 0/1): acc -> LDS (stride 136 bf16,
//    16B-aligned, bank-spread) -> bf16x8 vector mask+store. 128 scalar ops
//    -> 16 vector ops per thread. Bit-identical numerics (mask is exact 0/1).

__device__ __forceinline__ void gld16(const bf16* g, bf16* l) {
  __builtin_amdgcn_global_load_lds((AS1 void*)g, (AS3 void*)l, 16, 0, 0);
}

__global__ void k_sentinel(float* __restrict__ out) {
  int i = blockIdx.x * 256 + threadIdx.x;
  if (i < 2097152) out[i] = 1048576.0f;
}

// ---------------- merged elementwise prep ----------------
// sections (256-thr blocks): s0 invln[1], s1 encWb[1536], s2 probsT[3072],
// s3 maskb[4096], s4 WOb[1152], s5 Xb[768], s6 BgTail[1536]  -> 12161 blocks
__global__ void k_prep(const float* __restrict__ lns, float* __restrict__ invln,
                       const float* __restrict__ enc_W, bf16* __restrict__ encWb,
                       const float* __restrict__ probs, bf16* __restrict__ probsT,
                       const int* __restrict__ cmask, bf16* __restrict__ maskb,
                       const float* __restrict__ W_O, bf16* __restrict__ WOb,
                       const float* __restrict__ resid, bf16* __restrict__ Xb,
                       bf16* __restrict__ BgTail, long ldTail) {
  const int bid = blockIdx.x, t = threadIdx.x;
  if (bid < 1) {                                  // s0: invln (1024)
    for (int k = 0; k < 4; k++) { int j = t + k * 256; invln[j] = 1.0f / lns[j]; }
  } else if (bid < 1537) {                        // s1: encWb cast (393216 v4)
    long idx = ((long)(bid - 1) * 256 + t) * 4;
    float4 v = *(const float4*)(enc_W + idx);
    bf16x4 o; o[0]=(bf16)v.x; o[1]=(bf16)v.y; o[2]=(bf16)v.z; o[3]=(bf16)v.w;
    *(bf16x4*)(encWb + idx) = o;
  } else if (bid < 4609) {                        // s2: probsT (786432 v4)
    long idx = ((long)(bid - 1537) * 256 + t) * 4;
    int s = (int)(idx & 255), q = (int)((idx >> 8) & 255);
    int hb = (int)(idx >> 16), h = hb % 12, b = hb / 12;
    float4 v = *(const float4*)(probs + idx);
    bf16x4 o; o[0]=(bf16)v.x; o[1]=(bf16)v.y; o[2]=(bf16)v.z; o[3]=(bf16)v.w;
    *(bf16x4*)(probsT + (long)b * 786432 + (long)q * 3072 + h * 256 + s) = o;
  } else if (bid < 8705) {                        // s3: maskb (1048576 v4)
    long idx = ((long)(bid - 4609) * 256 + t) * 4;
    int4 v = *(const int4*)(cmask + idx);
    bf16x4 o; o[0]=(bf16)(float)v.x; o[1]=(bf16)(float)v.y;
    o[2]=(bf16)(float)v.z; o[3]=(bf16)(float)v.w;
    *(bf16x4*)(maskb + idx) = o;
  } else if (bid < 9857) {                        // s4: WOb (294912 v4)
    long idx = ((long)(bid - 8705) * 256 + t) * 4;
    int o = (int)(idx % 768), r = (int)((idx / 768) & 127), h = (int)(idx / (768 * 128));
    bf16x4 ov;
    if (r < 64) {
      float4 v = *(const float4*)(W_O + (long)(h * 64 + r) * 768 + o);
      ov[0]=(bf16)v.x; ov[1]=(bf16)v.y; ov[2]=(bf16)v.z; ov[3]=(bf16)v.w;
    } else { ov[0]=ov[1]=ov[2]=ov[3]=(bf16)0.0f; }
    *(bf16x4*)(WOb + idx) = ov;
  } else if (bid < 10625) {                       // s5: Xb (196608 v4)
    long idx = ((long)(bid - 9857) * 256 + t) * 4;
    float il = 1.0f / lns[idx / 768];
    float4 v = *(const float4*)(resid + idx);
    bf16x4 o; o[0]=(bf16)(v.x*il); o[1]=(bf16)(v.y*il);
    o[2]=(bf16)(v.z*il); o[3]=(bf16)(v.w*il);
    *(bf16x4*)(Xb + idx) = o;
  } else {                                        // s6: B_g K-tail (393216 v4)
    long idx = ((long)(bid - 10625) * 256 + t) * 4;
    int f = (int)(idx / 768), d = (int)(idx % 768);
    float4 v = *(const float4*)(enc_W + idx);
    bf16x4 o; o[0]=(bf16)v.x; o[1]=(bf16)v.y; o[2]=(bf16)v.z; o[3]=(bf16)v.w;
    *(bf16x4*)(BgTail + (long)f * ldTail + d) = o;
  }
}

// ---------------- merged tiled transposes ----------------
// zones: WVt[1152] WOt[576] updWt[1536] Ut[2048] -> 5312 blocks
__global__ void k_prepT(const float* __restrict__ wv, bf16* __restrict__ WVt,
                        const float* __restrict__ wo, bf16* __restrict__ W_Ot,
                        const float* __restrict__ updW, bf16* __restrict__ updWt,
                        const float* __restrict__ pr, const float* __restrict__ lns,
                        bf16* __restrict__ Ut) {
  __shared__ float tile[32][33];
  const int bid = blockIdx.x;
  int lane = threadIdx.x & 31, rg = threadIdx.x >> 5;
  if (bid < 1152) {                 // WVt[h][k<128][i<768] = W_V[h,i,k]
    int r0 = bid;
    int x = r0 % 4, y = (r0 / 4) % 24, h = r0 / 96;
    int k0 = x * 32, i0 = y * 32;
    if (k0 < 64) {
      for (int r = rg; r < 32; r += 8)
        tile[r][lane] = wv[((long)(h * 768 + i0 + r)) * 64 + k0 + lane];
      __syncthreads();
      for (int r = rg; r < 32; r += 8)
        WVt[((long)h * 128 + k0 + r) * 768 + i0 + lane] = (bf16)tile[lane][r];
    } else {
      for (int r = rg; r < 32; r += 8)
        WVt[((long)h * 128 + k0 + r) * 768 + i0 + lane] = (bf16)0.0f;
    }
  } else if (bid < 1728) {          // W_Ot[h][o][k64] = W_O[h,k,o]
    int r0 = bid - 1152;
    int x = r0 % 2, y = (r0 / 2) % 24, h = r0 / 48;
    int k0 = x * 32, o0 = y * 32;
    for (int r = rg; r < 32; r += 8)
      tile[r][lane] = wo[((long)(h * 64 + k0 + r)) * 768 + o0 + lane];
    __syncthreads();
    for (int r = rg; r < 32; r += 8)
      W_Ot[((long)(h * 768 + o0 + r)) * 64 + k0 + lane] = (bf16)tile[lane][r];
  } else if (bid < 3264) {          // updWt[u][i] = up_dec_W[i][u]
    int r0 = bid - 1728;
    int u0 = (r0 % 64) * 32, i0 = (r0 / 64) * 32;
    for (int r = rg; r < 32; r += 8)
      tile[r][lane] = updW[((long)(i0 + r)) * 2048 + u0 + lane];
    __syncthreads();
    for (int r = rg; r < 32; r += 8)
      updWt[((long)(u0 + r)) * 768 + i0 + lane] = (bf16)tile[lane][r];
  } else {                          // Ut[b][u][s] = pruned[b,s,u]/ln
    int r0 = bid - 3264;
    int u0 = (r0 % 64) * 32, s0 = ((r0 / 64) % 8) * 32, b = r0 / 512;
    for (int r = rg; r < 32; r += 8) {
      int s = s0 + r;
      tile[r][lane] = pr[((long)(b * 256 + s)) * 2048 + u0 + lane] *
                      (1.0f / lns[b * 256 + s]);
    }
    __syncthreads();
    for (int r = rg; r < 32; r += 8)
      Ut[((long)b * 2048 + u0 + r) * 256 + s0 + lane] = (bf16)tile[lane][r];
  }
}

// reduce 4 fp32 split-K slabs of S and cast into the bf16 A_g K-tail
__global__ void k_sred(const float* __restrict__ Sp, bf16* __restrict__ dst, long ldd) {
  int i = blockIdx.x * 256 + threadIdx.x;   // 196608 vec4s
  if (i < 196608) {
    long idx = (long)i * 4;
    int m = (int)(idx / 768), o = (int)(idx % 768);
    float4 v = *(const float4*)(Sp + idx);
    float4 a = *(const float4*)(Sp + 786432 + idx);
    float4 b = *(const float4*)(Sp + 2 * 786432 + idx);
    float4 c = *(const float4*)(Sp + 3 * 786432 + idx);
    v.x += a.x + b.x + c.x; v.y += a.y + b.y + c.y;
    v.z += a.z + b.z + c.z; v.w += a.w + b.w + c.w;
    bf16x4 ov;
    ov[0] = (bf16)v.x; ov[1] = (bf16)v.y; ov[2] = (bf16)v.z; ov[3] = (bf16)v.w;
    *(bf16x4*)(dst + (long)m * ldd + o) = ov;
  }
}

// ---------------- bias chain (fp32, block-parallel) ----------------

__device__ __forceinline__ float blk_reduce(float s) {
  __shared__ float red[256];
  red[threadIdx.x] = s; __syncthreads();
  for (int o = 128; o > 0; o >>= 1) {
    if ((int)threadIdx.x < o) red[threadIdx.x] += red[threadIdx.x + o];
    __syncthreads();
  }
  float r = red[0]; __syncthreads();
  return r;
}

__global__ void k_bias_t(const float* __restrict__ W_V, const float* __restrict__ up_b,
                         float* __restrict__ t_hk) {
  int j = blockIdx.x, h = j >> 6, k = j & 63;
  float s = 0.f;
  for (int m = threadIdx.x; m < 768; m += 256)
    s += W_V[((long)(h * 768 + m)) * 64 + k] * up_b[m];
  float r = blk_reduce(s);
  if (threadIdx.x == 0) t_hk[j] = r;
}

__global__ void k_bias_w(const float* __restrict__ W_O, const float* __restrict__ t_hk,
                         float* __restrict__ w) {
  int d = blockIdx.x;
  float s = 0.f;
  for (int j = threadIdx.x; j < 768; j += 256)
    s += W_O[(long)j * 768 + d] * t_hk[j];
  float r = blk_reduce(s);
  if (threadIdx.x == 0) w[d] = r;
}

__global__ void k_bias_c(const float* __restrict__ enc_W, const float* __restrict__ enc_b,
                         const float* __restrict__ b_dec, const float* __restrict__ w,
                         float* __restrict__ c0, float* __restrict__ c1) {
  int f = blockIdx.x;
  float s0 = 0.f, s1 = 0.f;
  for (int d = threadIdx.x; d < 768; d += 256) {
    float e = enc_W[(long)f * 768 + d];
    s0 += e * b_dec[d];
    s1 += e * w[d];
  }
  float r0 = blk_reduce(s0);
  float r1 = blk_reduce(s1);
  if (threadIdx.x == 0) { c0[f] = enc_b[f] - r0; c1[f] = r1; }
}

// ---------------- GEMM (BT form: C[m,n] = sum_k A[m,k]*B[n,k]) ----------------
// BK=64, XOR-swizzled staging. K (and kChunk) must be multiples of 64.
// mode 0: bf16 store; mode 1: *= bf16 mask, bf16 store;
//   (modes 0/1 use an LDS-bounce vectorized epilogue: acc -> LDS -> bf16x8
//    vector mask-multiply + 16B stores; bit-identical to the scalar path)
// mode 2: split-K fp32 overwrite; mode 3: split-K fp32 read-accumulate;
// mode 4: batched split-K fp32 overwrite (z = bb*batchH + kc, batchH = #kc)
__global__ __launch_bounds__(256)
void gemm_bt(const bf16* __restrict__ A, const bf16* __restrict__ B, void* __restrict__ Cv,
             int M, int N, int K,
             long lda, long ldb, long ldc,
             int batchH,
             long sa_b, long sa_h, long sb_b, long sb_h, long sc_b, long sc_h,
             int mode, int kChunk,
             const bf16* __restrict__ mask, long mask_ld)
{
  __shared__ __align__(16) bf16 SMEM[16384];     // Asm | Bsm (and epilogue buf)
  bf16* Asm = SMEM;
  bf16* Bsm = SMEM + 8192;

  const int t = threadIdx.x;

  // bijective XCD-aware remap of the (x,y) tile id (m204 formula)
  const int nbx = gridDim.x, nby = gridDim.y;
  const int nxy = nbx * nby;
  int orig = blockIdx.x + nbx * blockIdx.y;
  int qq = nxy >> 3, rr = nxy & 7;
  int xcd = orig & 7, lid = orig >> 3;
  int swz = (xcd < rr) ? (xcd * (qq + 1) + lid)
                       : (rr * (qq + 1) + (xcd - rr) * qq + lid);
  const int m0 = (swz % nby) * 128;
  const int n0 = (swz / nby) * 128;

  long aoff, boff, coff;
  int k0, k1;
  if (mode == 4) {
    int z = blockIdx.z;
    int bb = z / batchH, kc = z - bb * batchH;
    aoff = (long)bb * sa_b;
    boff = (long)bb * sb_b;
    coff = (long)bb * sc_b + (long)kc * sc_h;
    k0 = kc * kChunk; k1 = k0 + kChunk; if (k1 > K) k1 = K;
  } else if (mode >= 2) {
    int z = blockIdx.z;
    aoff = 0; boff = 0;
    coff = (long)z * (long)M * ldc;
    k0 = z * kChunk; k1 = k0 + kChunk; if (k1 > K) k1 = K;
  } else {
    int z = blockIdx.z;
    int bb = z / batchH, hh = z - bb * batchH;
    aoff = (long)bb * sa_b + (long)hh * sa_h;
    boff = (long)bb * sb_b + (long)hh * sb_h;
    coff = (long)bb * sc_b + (long)hh * sc_h;
    k0 = 0; k1 = K;
  }

  const bf16* Ab = A + aoff + (long)m0 * lda;
  const bf16* Bb = B + boff + (long)n0 * ldb;

  const int r0 = t >> 3;           // 0..31 (staging row within 32-row group)
  const int g8 = t & 7;            // staging col-group (LDS slot)

  const int L = t & 63, w = t >> 6;
  const int wm = (w & 1) * 64, wn = (w >> 1) * 64;
  const int r16 = L & 15, q = L >> 4;

  f32x4 acc[4][4];
#pragma unroll
  for (int i = 0; i < 4; i++)
#pragma unroll
    for (int j = 0; j < 4; j++) acc[i][j] = (f32x4){0.f, 0.f, 0.f, 0.f};

  for (int kt = k0; kt < k1; kt += 64) {
#pragma unroll
    for (int j = 0; j < 4; j++) {
      int row = j * 32 + r0;
      int sc = ((g8 ^ (row & 7)) << 3);      // source col swizzle
      gld16(Ab + (long)row * lda + (kt + sc), &Asm[j * 2048 + t * 8]);
      gld16(Bb + (long)row * ldb + (kt + sc), &Bsm[j * 2048 + t * 8]);
    }
    __syncthreads();

#pragma unroll
    for (int h2 = 0; h2 < 2; h2++) {
      bf16x8 af[4], bfr[4];
#pragma unroll
      for (int i = 0; i < 4; i++) {
        int ra = wm + i * 16 + r16;
        af[i]  = *(const bf16x8*)&Asm[ra * 64 + ((((h2 << 2) + q) ^ (ra & 7)) << 3)];
        int rb = wn + i * 16 + r16;
        bfr[i] = *(const bf16x8*)&Bsm[rb * 64 + ((((h2 << 2) + q) ^ (rb & 7)) << 3)];
      }
#pragma unroll
      for (int mi = 0; mi < 4; mi++)
#pragma unroll
        for (int ni = 0; ni < 4; ni++)
          acc[mi][ni] = __builtin_amdgcn_mfma_f32_16x16x32_bf16(af[mi], bfr[ni], acc[mi][ni], 0, 0, 0);
    }
    __syncthreads();
  }

  if (mode >= 2) {
    float* C = (float*)Cv;
#pragma unroll
    for (int mi = 0; mi < 4; mi++)
#pragma unroll
      for (int ni = 0; ni < 4; ni++)
#pragma unroll
        for (int r = 0; r < 4; r++) {
          int gm = m0 + wm + mi * 16 + q * 4 + r;
          int gn = n0 + wn + ni * 16 + r16;
          long idx = coff + (long)gm * ldc + gn;
          float v = acc[mi][ni][r];
          if (mode == 3) v += C[idx];
          C[idx] = v;
        }
  } else {
    // LDS-bounce vectorized epilogue (modes 0/1). Processes the 128x128 tile
    // in two 64-row halves: half hh covers global rows {m0+32hh..+32} and
    // {m0+64+32hh..+32} (mi in {2hh, 2hh+1} for both wm halves).
    // lbuf stride 136 bf16 (272B): rows 16B-aligned, banks spread (272%128!=0).
    bf16* C = (bf16*)Cv;
    bf16* lbuf = SMEM;                        // 64*136*2 = 17408B <= 32KB
    const int lrbase = (wm >> 6) * 32 + q * 4;
    const int lr_r = t >> 2;                  // 0..63
    const int colg = (t & 3) * 32;            // 0,32,64,96
#pragma unroll
    for (int hh = 0; hh < 2; hh++) {
#pragma unroll
      for (int m2 = 0; m2 < 2; m2++) {
        int mi = hh * 2 + m2;
#pragma unroll
        for (int ni = 0; ni < 4; ni++) {
          int col = wn + ni * 16 + r16;
#pragma unroll
          for (int r = 0; r < 4; r++)
            lbuf[(lrbase + m2 * 16 + r) * 136 + col] = (bf16)acc[mi][ni][r];
        }
      }
      __syncthreads();
      int gm = m0 + (lr_r >> 5) * 64 + hh * 32 + (lr_r & 31);
#pragma unroll
      for (int s = 0; s < 4; s++) {
        bf16x8 v = *(const bf16x8*)&lbuf[lr_r * 136 + colg + 8 * s];
        int gn = n0 + colg + 8 * s;
        if (mode == 1) {
          bf16x8 mv = *(const bf16x8*)&mask[(long)gm * mask_ld + gn];
#pragma unroll
          for (int j = 0; j < 8; j++) v[j] = (bf16)((float)v[j] * (float)mv[j]);
        }
        *(bf16x8*)&C[coff + (long)gm * ldc + gn] = v;
      }
      __syncthreads();
    }
  }
}

// ------------- 256x256-tile split-K GEMM (final GEMM) ------------------------
// C[m,n] (+)= sum_k A[m,k]*B[n,k], fp32 C. 512 threads = 8 waves (2M x 4N),
// per-wave 128x64 output. BK=64. 2 LDS buffers (128 KiB), depth-1 prefetch,
// counted vmcnt(8) (0 only at epilogue), 2 barriers per K-step.  [R26 form]
// Work remap: z = fid % nz -> one K-slab per XCD (R24: FETCH 253->76MB).
// K, kChunk multiples of 64. mode 2 = overwrite, 3 = read-accumulate.
__global__ __launch_bounds__(512, 2)
void gemm_fp2(const bf16* __restrict__ A, const bf16* __restrict__ B,
              float* __restrict__ C,
              int M, int N, int K, long lda, long ldb, long ldc,
              int mode, int kChunk)
{
  __shared__ __align__(16) bf16 SM[2][2][16384];   // [buf][A|B][256*64]

  const int t = threadIdx.x;

  const int nz = gridDim.z;
  int fid = blockIdx.x + gridDim.x * (blockIdx.y + gridDim.y * blockIdx.z);
  const int z  = fid % nz;                 // K-slab, constant per XCD when nz=8
  const int t2 = fid / nz;                 // 0..31 (m,n)-tile within the slab
  const int m0 = (t2 >> 3) * 256;          // 4 m-tiles
  const int n0 = (t2 & 7) * 256;           // 8 n-tiles

  const long coff = (long)z * (long)M * ldc;
  int k0 = z * kChunk, k1 = k0 + kChunk; if (k1 > K) k1 = K;
  const int NT = (k1 > k0) ? (k1 - k0) >> 6 : 0;

  const bf16* Ab = A + (long)m0 * lda + k0;
  const bf16* Bb = B + (long)n0 * ldb + k0;

  const int sr = t >> 3;           // 0..63 staging row within 64-row group
  const int g8 = t & 7;            // staging col-group (LDS slot)

  const int L = t & 63, w = t >> 6;          // 8 waves
  const int wm = (w & 1) * 128;              // 2 waves over M (256)
  const int wn = (w >> 1) * 64;              // 4 waves over N (256)
  const int r16 = L & 15, q = L >> 4;

  f32x4 acc[8][4];
#pragma unroll
  for (int i = 0; i < 8; i++)
#pragma unroll
    for (int j = 0; j < 4; j++) acc[i][j] = (f32x4){0.f, 0.f, 0.f, 0.f};

  // stage K-tile tt into buffer buf: 8 gld16 per thread (4 A rounds, 4 B)
  auto stage = [&](int tt, int buf) {
    const bf16* Ap = Ab + (long)tt * 64;
    const bf16* Bp = Bb + (long)tt * 64;
#pragma unroll
    for (int j = 0; j < 4; j++) {
      int row = j * 64 + sr;
      int sc = ((g8 ^ (row & 7)) << 3);
      gld16(Ap + (long)row * lda + sc, &SM[buf][0][j * 4096 + t * 8]);
    }
#pragma unroll
    for (int j = 0; j < 4; j++) {
      int row = j * 64 + sr;
      int sc = ((g8 ^ (row & 7)) << 3);
      gld16(Bp + (long)row * ldb + sc, &SM[buf][1][j * 4096 + t * 8]);
    }
  };

  if (NT >= 1) stage(0, 0);

  for (int tt = 0; tt < NT; tt++) {
    if (tt + 1 < NT) {
      stage(tt + 1, (tt + 1) & 1);           // prefetch next into other buffer
      asm volatile("s_waitcnt vmcnt(8)" ::: "memory");   // stage(tt) done
    } else {
      asm volatile("s_waitcnt vmcnt(0)" ::: "memory");   // epilogue drain
    }
    __builtin_amdgcn_s_barrier();            // buffer tt&1 ready for all waves

    const bf16* As = &SM[tt & 1][0][0];
    const bf16* Bs = &SM[tt & 1][1][0];
#pragma unroll
    for (int h2 = 0; h2 < 2; h2++) {
      bf16x8 af[8], bfr[4];
#pragma unroll
      for (int i = 0; i < 8; i++) {
        int ra = wm + i * 16 + r16;
        af[i]  = *(const bf16x8*)&As[ra * 64 + ((((h2 << 2) + q) ^ (ra & 7)) << 3)];
      }
#pragma unroll
      for (int i = 0; i < 4; i++) {
        int rb = wn + i * 16 + r16;
        bfr[i] = *(const bf16x8*)&Bs[rb * 64 + ((((h2 << 2) + q) ^ (rb & 7)) << 3)];
      }
#pragma unroll
      for (int mi = 0; mi < 8; mi++)
#pragma unroll
        for (int ni = 0; ni < 4; ni++)
          acc[mi][ni] = __builtin_amdgcn_mfma_f32_16x16x32_bf16(af[mi], bfr[ni], acc[mi][ni], 0, 0, 0);
    }
    __builtin_amdgcn_s_barrier();            // all waves done reading buf tt&1
  }

#pragma unroll
  for (int mi = 0; mi < 8; mi++)
#pragma unroll
    for (int ni = 0; ni < 4; ni++)
#pragma unroll
      for (int r = 0; r < 4; r++) {
        int gm = m0 + wm + mi * 16 + q * 4 + r;
        int gn = n0 + wn + ni * 16 + r16;
        long idx = coff + (long)gm * ldc + gn;
        float v = acc[mi][ni][r];
        if (mode == 3) v += C[idx];
        C[idx] = v;
      }
}

// ---------------- final reduce + bias epilogue (fp32 out, float4) ------------
__global__ void k_out(const float* __restrict__ Cp, const float* __restrict__ c0,
                      const float* __restrict__ c1, const float* __restrict__ invln,
                      float* __restrict__ out, int nsplit) {
  int i4 = blockIdx.x * 256 + threadIdx.x;          // 524288
  long i = (long)i4 * 4;
  int n = (int)(i & 2047), m = (int)(i >> 11);
  float4 v = *(const float4*)(Cp + i);
  for (int z = 1; z < nsplit; z++) {
    float4 u = *(const float4*)(Cp + i + (long)z * 2097152);
    v.x += u.x; v.y += u.y; v.z += u.z; v.w += u.w;
  }
  float il = invln[m];
  float4 a = *(const float4*)(c0 + n);
  float4 b = *(const float4*)(c1 + n);
  v.x += a.x + b.x * il;
  v.y += a.y + b.y * il;
  v.z += a.z + b.z * il;
  v.w += a.w + b.w * il;
  *(float4*)(out + i) = v;
}

// ---------------- host ----------------

extern "C" void kernel_launch(void* const* d_in, const int* in_sizes, int n_in,
                              void* d_out, int out_size, void* d_ws, size_t ws_size,
                              hipStream_t stream) {
  (void)out_size;
  float* out = (float*)d_out;

  // ---- resolve inputs by size (order-agnostic) ----
  int iresid = -1, iln = -1, iprobs = -1, iencb = -1, ipruned = -1, imask = -1;
  int iwo = -1, iwv = -1, iencw = -1, iupdw = -1, ibdec = -1, iupb = -1;
  for (int i = 0; i < n_in; i++) {
    switch (in_sizes[i]) {
      case 786432:  iresid  = i; break;
      case 1024:    iln     = i; break;
      case 3145728: iprobs  = i; break;
      case 2048:    iencb   = i; break;
      case 2097152: ipruned = i; break;
      case 4194304: imask   = i; break;
      case 589824:  if (iwo   < 0) iwo   = i; else iwv   = i; break;
      case 1572864: if (iencw < 0) iencw = i; else iupdw = i; break;
      case 768:     if (ibdec < 0) ibdec = i; else iupb  = i; break;
      default: break;
    }
  }
  bool ok = n_in == 12 && iresid >= 0 && iln >= 0 && iprobs >= 0 && iencb >= 0 &&
            ipruned >= 0 && imask >= 0 && iwo >= 0 && iwv >= 0 && iencw >= 0 &&
            iupdw >= 0 && ibdec >= 0 && iupb >= 0;
  if (!ok) { k_sentinel<<<8192, 256, 0, stream>>>(out); return; }

  const float* resid = (const float*)d_in[iresid];
  const float* lns   = (const float*)d_in[iln];
  const float* probs = (const float*)d_in[iprobs];
  const float* W_O   = (const float*)d_in[iwo];
  const float* W_V   = (const float*)d_in[iwv];
  const float* enc_W = (const float*)d_in[iencw];
  const float* enc_b = (const float*)d_in[iencb];
  const float* b_dec = (const float*)d_in[ibdec];
  const float* updW  = (const float*)d_in[iupdw];
  const float* up_b  = (const float*)d_in[iupb];
  const float* pruned= (const float*)d_in[ipruned];
  const int*   cmask = (const int*)d_in[imask];

  // ---- workspace sizing ----
  auto pad = [](size_t b) -> size_t { return (b + 255) & ~(size_t)255; };
  const size_t prepB = pad(2359296) + pad(2359296) + pad(3145728) + pad(1572864) +
                       pad(3145728) + pad(1179648) + pad(3145728) + pad(18874368) +
                       pad(12582912);
  const size_t persB = pad(6291456) + pad(4194304) + pad(6291456) + pad(6291456) +
                       pad(8388608) + pad(4096) + pad(3072) + pad(3072) +
                       pad(8192) + pad(8192);
  auto needB = [&](int g, int ns) -> size_t {
    size_t cp = (size_t)ns * 8388608;
    size_t ov = prepB > cp ? prepB : cp;
    long KA = (long)g * 2048 + 768;
    size_t ab = pad((size_t)1024 * KA * 2) + pad((size_t)2048 * KA * 2);
    return ov + persB + ab + (2ull << 20);   // 2MiB slack
  };
  // prefer gs=12 (one final GEMM) + nsplit=8 (grid (8,4,8)=256 blocks = 1/CU)
  const int cgs[14] = {12, 12, 12, 6, 6, 4, 3, 2, 2, 1, 1, 1, 1, 1};
  const int cns[14] = { 8,  4, 2, 8, 4, 4, 4, 4, 2, 8, 4, 2, 2, 1};
  int gs = 0, nsplit = 0;
  for (int ci = 0; ci < 14; ci++) {
    if (needB(cgs[ci], cns[ci]) <= ws_size) { gs = cgs[ci]; nsplit = cns[ci]; break; }
  }
  if (gs == 0) { gs = 1; nsplit = 1; }

  const long KA = (long)gs * 2048 + 768;     // A_g/B_g leading dim (K incl. tail)

  char* p = (char*)d_ws;
  auto alloc = [&](size_t bytes) -> char* {
    char* r = p; p += (bytes + 255) & ~(size_t)255; return r;
  };
  // -- overlay region: prep buffers, later reused as Cpart --
  char* overlayBase = p;
  bf16*  WOb    = (bf16*)alloc(12ull * 128 * 768 * 2);
  bf16*  WVt    = (bf16*)alloc(12ull * 128 * 768 * 2);
  bf16*  updWt  = (bf16*)alloc(2048ull * 768 * 2);
  bf16*  Xb     = (bf16*)alloc(1024ull * 768 * 2);
  bf16*  encWb  = (bf16*)alloc(2048ull * 768 * 2);
  bf16*  W_Ot   = (bf16*)alloc(12ull * 768 * 64 * 2);
  bf16*  T1     = (bf16*)alloc(12ull * 1024 * 128 * 2);
  bf16*  T3     = (bf16*)alloc(4ull * 768 * 3072 * 2);
  float* Sp     = (float*)alloc(4ull * 1024 * 768 * 4);
  {
    size_t used = (size_t)(p - overlayBase);
    size_t cp = (size_t)nsplit * 8388608;
    p = overlayBase + (used > cp ? used : cp);
  }
  float* Cpart  = (float*)overlayBase;       // aliases dead prep buffers
  // -- persistent region --
  bf16*  G_t    = (bf16*)alloc(12ull * 2048 * 128 * 2);
  bf16*  Ut     = (bf16*)alloc(4ull * 2048 * 256 * 2);
  bf16*  E1     = (bf16*)alloc(12ull * 2048 * 128 * 2);
  bf16*  probsT = (bf16*)alloc(4ull * 256 * 3072 * 2);
  bf16*  maskb  = (bf16*)alloc(2048ull * 2048 * 2);
  float* invln  = (float*)alloc(1024 * 4);
  float* t_hk   = (float*)alloc(768 * 4);
  float* wv     = (float*)alloc(768 * 4);
  float* c0     = (float*)alloc(2048 * 4);
  float* c1     = (float*)alloc(2048 * 4);
  bf16*  A_g    = (bf16*)alloc((size_t)1024 * KA * 2);
  bf16*  B_g    = (bf16*)alloc((size_t)2048 * KA * 2);

  // ---- prep (2 merged kernels + bias chain) ----
  k_prep<<<12161, 256, 0, stream>>>(lns, invln, enc_W, encWb, probs, probsT,
                                    cmask, maskb, W_O, WOb, resid, Xb,
                                    B_g + (long)gs * 2048, KA);
  k_prepT<<<5312, 256, 0, stream>>>(W_V, WVt, W_O, W_Ot, updW, updWt,
                                    pruned, lns, Ut);
  k_bias_t<<<768, 256, 0, stream>>>(W_V, up_b, t_hk);
  k_bias_w<<<768, 256, 0, stream>>>(W_O, t_hk, wv);
  k_bias_c<<<2048, 256, 0, stream>>>(enc_W, enc_b, b_dec, wv, c0, c1);

  // Merged E1 + G_t (z = 24, bb selects the problem via pointer-diff strides):
  //   bb=0: E1[h][f][k]  = encWb[f,o] . WOb[h][k][o]
  //   bb=1: G_t[h][u][k] = updWt[u,i] . WVt[h][k][i]
  gemm_bt<<<dim3(1, 16, 24), 256, 0, stream>>>(
      encWb, WOb, E1, 2048, 128, 768,
      768, 768, 128, 12,
      (long)(updWt - encWb), 0,
      (long)(WVt - WOb), (long)128 * 768,
      (long)(G_t - E1), (long)2048 * 128,
      0, 0, nullptr, 0);

  // ---- init path: T1 -> T3 -> S (split-K) -> reduce into A_g K-tail ----
  // T1[h][bs][k128] = Xb[bs,i] . WVt[h][k][i]   M=1024 N=128 K=768 (z=h)
  gemm_bt<<<dim3(1, 8, 12), 256, 0, stream>>>(
      Xb, WVt, T1, 1024, 128, 768,
      768, 768, 128, 12,
      0, 0, 0, (long)128 * 768, 0, (long)1024 * 128,
      0, 0, nullptr, 0);

  // T3[b][o][h*256+s] = W_Ot[h][o][k] . T1[h][b*256+s][k]   M=768 N=256 K=64
  gemm_bt<<<dim3(2, 6, 48), 256, 0, stream>>>(
      W_Ot, T1, T3, 768, 256, 64,
      64, 128, 3072, 12,
      0, (long)768 * 64, (long)256 * 128, (long)1024 * 128, 2359296, 256,
      0, 0, nullptr, 0);

  // S (mode 4, batched split-K): 16 z-blocks, kChunk=768 -> 12 K-steps each.
  gemm_bt<<<dim3(6, 2, 16), 256, 0, stream>>>(
      probsT, T3, Sp, 256, 768, 3072,
      3072, 3072, 768, 4,
      786432, 0, 2359296, 0, 196608, 786432,
      4, 768, nullptr, 0);

  // reduce 4 Sp slabs + cast -> A_g[:, gs*2048 .. +768]
  k_sred<<<768, 256, 0, stream>>>(Sp, A_g + (long)gs * 2048, KA);

  // ---- head-group loop (single iteration when gs==12) ----
  for (int g = 0; g < 12 / gs; g++) {
    // V_g: B_g[f][hh*2048+u] = maskb[f,u] * (E1_h[f,k] . G_t_h[u,k])  K=64
    gemm_bt<<<dim3(16, 16, gs), 256, 0, stream>>>(
        E1 + (long)g * gs * 2048 * 128, G_t + (long)g * gs * 2048 * 128, B_g,
        2048, 2048, 64,
        128, 128, KA, gs,
        0, (long)2048 * 128, 0, (long)2048 * 128, 0, 2048,
        1, 0, maskb, 2048);

    // PU_g: A_g[b*256+q][hh*2048+u] = probsT[b][q][(g*gs+hh)*256 + s] . Ut[b][u][s]
    gemm_bt<<<dim3(16, 2, 4 * gs), 256, 0, stream>>>(
        probsT + (long)g * gs * 256, Ut, A_g,
        256, 2048, 256,
        3072, 256, KA, gs,
        786432, 256, (long)2048 * 256, 0, 256 * KA, 2048,
        0, 0, nullptr, 0);

    // Cpart (+)= A_g[bq,k] . B_g[f,k]  -- 256x256-tile (R26 form)
    int Kthis = (g == 0) ? (int)KA : gs * 2048;
    int kc = ((Kthis / nsplit + 63) / 64) * 64;
    gemm_fp2<<<dim3(8, 4, nsplit), 512, 0, stream>>>(
        A_g, B_g, Cpart,
        1024, 2048, Kthis,
        KA, KA, 2048,
        (g == 0) ? 2 : 3, kc);
  }

  // out[b,q,f] = fp32( sum_z Cpart + c0[f] + c1[f]*invln[bq] )
  k_out<<<2048, 256, 0, stream>>>(Cpart, c0, c1, invln, out, nsplit);
}